// Round 12
// baseline (33.760 us; speedup 1.0000x reference)
//
#include <hip/hip_runtime.h>
#include <hip/hip_bf16.h>

#define BB 8
#define SS 2048
#define EE 8
#define FF 4096
#define NTOK (BB*SS)

using bf16x8 = __attribute__((ext_vector_type(8))) short;
using f32x4  = __attribute__((ext_vector_type(4))) float;

// ---- workspace layout (float offsets) ----
constexpr int O_FLAG  = 0;
constexpr int O_WPRE  = 8;      // 64
constexpr int O_BPRE  = 72;     // 8
constexpr int O_THQ   = 80;     // 8
constexpr int O_THK   = 88;     // 8
constexpr int O_THV   = 96;     // 8
constexpr int O_WCOMB = 104;    // 64
constexpr int O_BCOMB = 168;    // 8
constexpr int O_G1    = 176;    // 8
constexpr int O_BE1   = 184;    // 8
constexpr int O_G2    = 192;    // 8
constexpr int O_BE2   = 200;    // 8
constexpr int O_WPREF = 208;    // 64
constexpr int O_BPREF = 272;    // 8
constexpr int O_THF   = 280;    // 8
constexpr int O_B2    = 288;    // 8
constexpr int O_W1T   = 512;             // fallback
constexpr int O_B1F   = O_W1T + FF*8;
constexpr int O_W2F   = O_B1F + FF;
constexpr int O_X     = O_W2F + FF*8;    // fallback path only
constexpr int O_K     = O_X + NTOK*EE;   // fallback attn
constexpr int O_V     = O_K + NTOK*EE;   // fallback attn
constexpr int O_H     = O_V + NTOK*EE;   // fallback
constexpr int O_P     = O_H + NTOK*EE;   // unused (layout stability)
constexpr int O_QFB   = O_P + 8*NTOK*EE; // unused on fused path
constexpr int O_W1A   = O_QFB + NTOK*4;  // 65536 f
constexpr int O_W2B   = O_W1A + 65536;   // 32768 f
constexpr int O_QB    = O_W2B + 32768;   // NTOK*4
constexpr int O_KB    = O_QB + NTOK*4;   // NTOK*4
constexpr int O_VTB   = O_KB + NTOK*4;   // 65536 f
constexpr size_t WS_MFMA = (size_t)(O_VTB + 65536) * 4;

__device__ __forceinline__ float b2f(unsigned short u) {
  return __uint_as_float(((unsigned)u) << 16);
}

__device__ __forceinline__ unsigned short f2bf(float f) {
  unsigned u = __float_as_uint(f);
  unsigned r = (u + 0x7fffu + ((u >> 16) & 1u)) >> 16;
  return (unsigned short)r;
}

// pack two f32 -> bf16x2 (a at low half = element 0)
__device__ __forceinline__ unsigned pk2(float a, float b) {
  unsigned ua = __float_as_uint(a) + 0x8000u;
  unsigned ub = __float_as_uint(b) + 0x8000u;
  return __builtin_amdgcn_perm(ub, ua, 0x07060302u);
}

__device__ __forceinline__ float loadin(const void* p, int i, int isf) {
  if (isf) return reinterpret_cast<const float*>(p)[i];
  return b2f(reinterpret_cast<const unsigned short*>(p)[i]);
}

// vectorized 8-element input row load (token granularity)
__device__ __forceinline__ void loadx8(const void* x, int tok, int isf, float* xv) {
  if (isf) {
    float4 a = reinterpret_cast<const float4*>(x)[tok * 2];
    float4 b = reinterpret_cast<const float4*>(x)[tok * 2 + 1];
    xv[0] = a.x; xv[1] = a.y; xv[2] = a.z; xv[3] = a.w;
    xv[4] = b.x; xv[5] = b.y; xv[6] = b.z; xv[7] = b.w;
  } else {
    uint4 u = reinterpret_cast<const uint4*>(x)[tok];
    xv[0] = __uint_as_float(u.x << 16); xv[1] = __uint_as_float(u.x & 0xffff0000u);
    xv[2] = __uint_as_float(u.y << 16); xv[3] = __uint_as_float(u.y & 0xffff0000u);
    xv[4] = __uint_as_float(u.z << 16); xv[5] = __uint_as_float(u.z & 0xffff0000u);
    xv[6] = __uint_as_float(u.w << 16); xv[7] = __uint_as_float(u.w & 0xffff0000u);
  }
}

// Wave-cooperative dtype sniff (see earlier rounds); P(misdetect)~2e-17.
__device__ __forceinline__ int detect_f32_wave(const void* x) {
  unsigned u = reinterpret_cast<const unsigned*>(x)[threadIdx.x & 63];
  float v = b2f((unsigned short)u);
  int bad = !(fabsf(v) <= 1e4f);
  return __ballot(bad) != 0ull;
}

// <Z_k>: c = cos(z+theta); out_k = prod_{i<=k} c_i (k>=1); out_0 = prod_{i=1..7} c_i
__device__ __forceinline__ void qproj(const float* qin, const float* th, float* out) {
  float c[8];
#pragma unroll
  for (int i = 0; i < 8; ++i) c[i] = __cosf(qin[i] + th[i]);
  float p = c[1];
#pragma unroll
  for (int i = 2; i < 8; ++i) p *= c[i];
  out[0] = p;
  float r = c[0];
#pragma unroll
  for (int i = 1; i < 8; ++i) { r *= c[i]; out[i] = r; }
}

__device__ __forceinline__ void layernorm8(const float* z, const float* g, const float* b, float* y) {
  float m = 0.f;
#pragma unroll
  for (int i = 0; i < 8; ++i) m += z[i];
  m *= 0.125f;
  float v = 0.f;
#pragma unroll
  for (int i = 0; i < 8; ++i) { float d = z[i] - m; v += d * d; }
  v *= 0.125f;
  float rs = rsqrtf(v + 1e-5f);
#pragma unroll
  for (int i = 0; i < 8; ++i) y[i] = (z[i] - m) * rs * g[i] + b[i];
}

// ==== prep helpers (proven) ====

__device__ __forceinline__ void prep_token_mfma(
    int tok, const void* x, const void* w_pre, const void* b_pre,
    const void* th_q, const void* th_k, const void* th_v,
    float* __restrict__ ws, int isf) {
  float xv[8];
  loadx8(x, tok, isf, xv);
  float qin[8];
#pragma unroll
  for (int i = 0; i < 8; ++i) {
    float a = loadin(b_pre, i, isf);
#pragma unroll
    for (int d = 0; d < 8; ++d) a = fmaf(xv[d], loadin(w_pre, d * 8 + i, isf), a);
    qin[i] = a;
  }
  float thq[8], thk[8], thv[8];
#pragma unroll
  for (int i = 0; i < 8; ++i) {
    thq[i] = loadin(th_q, i, isf);
    thk[i] = loadin(th_k, i, isf);
    thv[i] = loadin(th_v, i, isf);
  }
  float qv[8], kv[8], vv[8];
  qproj(qin, thq, qv);
  qproj(qin, thk, kv);
  qproj(qin, thv, vv);
  const float sc = 0.510120927f;  // log2(e)/sqrt(8)
  uint4 uq, uk;
  uq.x = (unsigned)f2bf(qv[0] * sc) | ((unsigned)f2bf(qv[1] * sc) << 16);
  uq.y = (unsigned)f2bf(qv[2] * sc) | ((unsigned)f2bf(qv[3] * sc) << 16);
  uq.z = (unsigned)f2bf(qv[4] * sc) | ((unsigned)f2bf(qv[5] * sc) << 16);
  uq.w = (unsigned)f2bf(qv[6] * sc) | ((unsigned)f2bf(qv[7] * sc) << 16);
  uk.x = (unsigned)f2bf(kv[0]) | ((unsigned)f2bf(kv[1]) << 16);
  uk.y = (unsigned)f2bf(kv[2]) | ((unsigned)f2bf(kv[3]) << 16);
  uk.z = (unsigned)f2bf(kv[4]) | ((unsigned)f2bf(kv[5]) << 16);
  uk.w = (unsigned)f2bf(kv[6]) | ((unsigned)f2bf(kv[7]) << 16);
  reinterpret_cast<uint4*>(ws + O_QB)[tok] = uq;
  reinterpret_cast<uint4*>(ws + O_KB)[tok] = uk;
  unsigned short* vtb = reinterpret_cast<unsigned short*>(ws + O_VTB);
#pragma unroll
  for (int i = 0; i < 8; ++i) vtb[i * NTOK + tok] = f2bf(vv[i]);
}

__device__ __forceinline__ void prep_w1a(int idx, const void* w1, const void* b1,
                                         float* __restrict__ ws, int isf) {
  const int T = idx >> 6, l = idx & 63, c = l & 15, g = l >> 4;
  const int j = T * 16 + c;
  float f[8];
#pragma unroll
  for (int e = 0; e < 8; ++e) f[e] = 0.f;
  if (g == 0) {
#pragma unroll
    for (int e = 0; e < 8; ++e) f[e] = loadin(w1, e * FF + j, isf);
  } else if (g == 1) {
    f[0] = loadin(b1, j, isf);
  }
  uint4 u;
  u.x = (unsigned)f2bf(f[0]) | ((unsigned)f2bf(f[1]) << 16);
  u.y = (unsigned)f2bf(f[2]) | ((unsigned)f2bf(f[3]) << 16);
  u.z = (unsigned)f2bf(f[4]) | ((unsigned)f2bf(f[5]) << 16);
  u.w = (unsigned)f2bf(f[6]) | ((unsigned)f2bf(f[7]) << 16);
  reinterpret_cast<uint4*>(ws + O_W1A)[idx] = u;
}

__device__ __forceinline__ void prep_w2b(int idx2, const void* w2,
                                         float* __restrict__ ws, int isf) {
  const int W = idx2 >> 6, l = idx2 & 63, i = l & 15, g = l >> 4;
  float f[8];
#pragma unroll
  for (int e = 0; e < 8; ++e) f[e] = 0.f;
  if (i < 8) {
#pragma unroll
    for (int e = 0; e < 8; ++e) {
      const int j = W * 32 + 16 * (e >> 2) + 4 * g + (e & 3);  // pi-permutation
      f[e] = loadin(w2, j * 8 + i, isf);
    }
  }
  uint4 u;
  u.x = (unsigned)f2bf(f[0]) | ((unsigned)f2bf(f[1]) << 16);
  u.y = (unsigned)f2bf(f[2]) | ((unsigned)f2bf(f[3]) << 16);
  u.z = (unsigned)f2bf(f[4]) | ((unsigned)f2bf(f[5]) << 16);
  u.w = (unsigned)f2bf(f[6]) | ((unsigned)f2bf(f[7]) << 16);
  reinterpret_cast<uint4*>(ws + O_W2B)[idx2] = u;
}

// ---- kernel A (fused prep): grid 177 x 256 (proven) ----
__global__ __launch_bounds__(256) void prep_all(
    const void* x, const void* w_pre, const void* b_pre, const void* th_q,
    const void* th_k, const void* th_v, const void* w_comb, const void* b_comb,
    const void* g1, const void* be1, const void* g2, const void* be2,
    const void* w_pre_f, const void* b_pre_f, const void* th_f,
    const void* w1, const void* b1, const void* w2, const void* b2,
    float* __restrict__ ws, int mfma_ok) {
  const int bid = blockIdx.x, tid = threadIdx.x;
  const int isf = detect_f32_wave(x);
  if (bid < 64) {
    const int tok = bid * 256 + tid;
    if (mfma_ok) {
      prep_token_mfma(tok, x, w_pre, b_pre, th_q, th_k, th_v, ws, isf);
    } else {
      float xv[8];
      loadx8(x, tok, isf, xv);
      float qin[8];
#pragma unroll
      for (int i = 0; i < 8; ++i) {
        float a = loadin(b_pre, i, isf);
#pragma unroll
        for (int d = 0; d < 8; ++d) a = fmaf(xv[d], loadin(w_pre, d * 8 + i, isf), a);
        qin[i] = a;
      }
      float thq[8], thk[8], thv[8];
#pragma unroll
      for (int i = 0; i < 8; ++i) {
        thq[i] = loadin(th_q, i, isf);
        thk[i] = loadin(th_k, i, isf);
        thv[i] = loadin(th_v, i, isf);
      }
      float qv[8], kv[8], vv[8];
      qproj(qin, thq, qv);
      qproj(qin, thk, kv);
      qproj(qin, thv, vv);
      float4* xp = reinterpret_cast<float4*>(ws + O_X + tok * 8);
      xp[0] = make_float4(xv[0], xv[1], xv[2], xv[3]);
      xp[1] = make_float4(xv[4], xv[5], xv[6], xv[7]);
      float4* kp = reinterpret_cast<float4*>(ws + O_K + tok * 8);
      float4* vp = reinterpret_cast<float4*>(ws + O_V + tok * 8);
      kp[0] = make_float4(kv[0], kv[1], kv[2], kv[3]);
      kp[1] = make_float4(kv[4], kv[5], kv[6], kv[7]);
      vp[0] = make_float4(vv[0], vv[1], vv[2], vv[3]);
      vp[1] = make_float4(vv[4], vv[5], vv[6], vv[7]);
    }
  } else if (bid < 128) {
    if (!mfma_ok) return;
    prep_w1a((bid - 64) * 256 + tid, w1, b1, ws, isf);
  } else if (bid < 160) {
    if (!mfma_ok) return;
    prep_w2b((bid - 128) * 256 + tid, w2, ws, isf);
  } else if (bid == 160) {
    if (tid < 64) {
      ws[O_WPRE + tid]  = loadin(w_pre, tid, isf);
      ws[O_WCOMB + tid] = loadin(w_comb, tid, isf);
      ws[O_WPREF + tid] = loadin(w_pre_f, tid, isf);
    }
    if (tid < 8) {
      ws[O_BPRE + tid]  = loadin(b_pre, tid, isf);
      ws[O_THQ + tid]   = loadin(th_q, tid, isf);
      ws[O_THK + tid]   = loadin(th_k, tid, isf);
      ws[O_THV + tid]   = loadin(th_v, tid, isf);
      ws[O_BCOMB + tid] = loadin(b_comb, tid, isf);
      ws[O_G1 + tid]    = loadin(g1, tid, isf);
      ws[O_BE1 + tid]   = loadin(be1, tid, isf);
      ws[O_G2 + tid]    = loadin(g2, tid, isf);
      ws[O_BE2 + tid]   = loadin(be2, tid, isf);
      ws[O_BPREF + tid] = loadin(b_pre_f, tid, isf);
      ws[O_THF + tid]   = loadin(th_f, tid, isf);
      ws[O_B2 + tid]    = loadin(b2, tid, isf);
    }
    if (tid == 0) ws[O_FLAG] = (float)isf;
  } else {
    if (mfma_ok) return;
    const int j = (bid - 161) * 256 + tid;
    ws[O_B1F + j] = loadin(b1, j, isf);
#pragma unroll
    for (int i = 0; i < 8; ++i) {
      ws[O_W1T + j * 8 + i] = loadin(w1, i * FF + j, isf);
      ws[O_W2F + j * 8 + i] = loadin(w2, j * 8 + i, isf);
    }
  }
}

// ==== fused attn+ffn body, 32 tokens/block, 512 blocks x 512 thr ====
// R11 body + 1-window software prefetch of K/V in the attention loop.
__device__ __forceinline__ void attn_ffn_body(const void* __restrict__ x,
                                              const float* __restrict__ ws,
                                              void* __restrict__ out, int isf) {
  __shared__ float Olds[8][32][8];     // 8 KB
  __shared__ float Llds[8][32];        // 1 KB
  __shared__ float Hlds[32][8];        // 1 KB
  __shared__ unsigned Qflds[32 * 4];   // 0.5 KB
  const int tid = threadIdx.x;
  const int wv = tid >> 6, l = tid & 63;
  const int c = l & 15, g = l >> 4;
  const int tokbase = blockIdx.x * 32;
  const int batch = blockIdx.x >> 6;   // 64 blocks per batch

  const bf16x8 zerov = (bf16x8)(short)0;
  const f32x4 zero = {0.f, 0.f, 0.f, 0.f};

  // ---- phase 1: attention (wave wv covers keys [batch*SS + wv*256, +256)) ----
  bf16x8 qb0 = zerov, qb1 = zerov;
  if (g == 0) {
    const bf16x8* qp = reinterpret_cast<const bf16x8*>(ws + O_QB) + tokbase + c;
    qb0 = qp[0]; qb1 = qp[16];
  }
  const bf16x8* Kb = reinterpret_cast<const bf16x8*>(ws + O_KB);
  const unsigned short* vtb = reinterpret_cast<const unsigned short*>(ws + O_VTB);

  f32x4 oacc0 = zero, oacc1 = zero;
  float ls0 = 0.f, ls1 = 0.f;
  const int kbase = batch * SS + wv * 256;

  // prefetch window 0
  bf16x8 kf0 = zerov, kf1 = zerov;
  union VFu { uint2 u[2]; bf16x8 v; };
  VFu VF;
  VF.u[0] = make_uint2(0u, 0u);
  VF.u[1] = make_uint2(0u, 0u);
  {
    const int kt = kbase;
    if (g == 0) {
      kf0 = Kb[kt + c];
      kf1 = Kb[kt + 16 + c];
    }
    if (c < 8) {
      VF.u[0] = *reinterpret_cast<const uint2*>(vtb + c * NTOK + kt + 4 * g);
      VF.u[1] = *reinterpret_cast<const uint2*>(vtb + c * NTOK + kt + 16 + 4 * g);
    }
  }

  for (int w = 0; w < 8; ++w) {
    // issue next window's loads before computing current (hide L2 latency)
    bf16x8 nkf0 = zerov, nkf1 = zerov;
    VFu nVF;
    nVF.u[0] = make_uint2(0u, 0u);
    nVF.u[1] = make_uint2(0u, 0u);
    if (w < 7) {
      const int nkt = kbase + (w + 1) * 32;
      if (g == 0) {
        nkf0 = Kb[nkt + c];
        nkf1 = Kb[nkt + 16 + c];
      }
      if (c < 8) {
        nVF.u[0] = *reinterpret_cast<const uint2*>(vtb + c * NTOK + nkt + 4 * g);
        nVF.u[1] = *reinterpret_cast<const uint2*>(vtb + c * NTOK + nkt + 16 + 4 * g);
      }
    }
#define ATT_QT(QB, OACC, LS)                                                     \
    {                                                                            \
      f32x4 s0 = __builtin_amdgcn_mfma_f32_16x16x32_bf16(kf0, QB, zero, 0,0,0);  \
      f32x4 s1 = __builtin_amdgcn_mfma_f32_16x16x32_bf16(kf1, QB, zero, 0,0,0);  \
      float p0[4], p1[4];                                                        \
      _Pragma("unroll")                                                          \
      for (int r = 0; r < 4; ++r) {                                              \
        p0[r] = __builtin_amdgcn_exp2f(s0[r]);                                   \
        p1[r] = __builtin_amdgcn_exp2f(s1[r]);                                   \
        LS += p0[r] + p1[r];                                                     \
      }                                                                          \
      union { unsigned u[4]; bf16x8 v; } PA;                                     \
      PA.u[0] = pk2(p0[0], p0[1]);                                               \
      PA.u[1] = pk2(p0[2], p0[3]);                                               \
      PA.u[2] = pk2(p1[0], p1[1]);                                               \
      PA.u[3] = pk2(p1[2], p1[3]);                                               \
      OACC = __builtin_amdgcn_mfma_f32_16x16x32_bf16(PA.v, VF.v, OACC, 0, 0, 0); \
    }
    ATT_QT(qb0, oacc0, ls0)
    ATT_QT(qb1, oacc1, ls1)
#undef ATT_QT
    if (w < 7) {
      kf0 = nkf0; kf1 = nkf1; VF = nVF;
    }
  }

  ls0 += __shfl_xor(ls0, 16); ls0 += __shfl_xor(ls0, 32);
  ls1 += __shfl_xor(ls1, 16); ls1 += __shfl_xor(ls1, 32);
  if (l < 16) {
    Llds[wv][l]      = ls0;
    Llds[wv][16 + l] = ls1;
  }
  if (c < 8) {
#pragma unroll
    for (int r = 0; r < 4; ++r) {
      Olds[wv][ 0 + 4 * g + r][c] = oacc0[r];
      Olds[wv][16 + 4 * g + r][c] = oacc1[r];
    }
  }
  __syncthreads();

  // ---- epilogue 1: combine, w_comb, residual, LN1, QF -> LDS ----
  if (tid < 32) {
    const int mytok = tokbase + tid;
    float lv = 0.f;
    float o[8];
#pragma unroll
    for (int i = 0; i < 8; ++i) o[i] = 0.f;
#pragma unroll
    for (int w = 0; w < 8; ++w) {
      lv += Llds[w][tid];
#pragma unroll
      for (int i = 0; i < 8; ++i) o[i] += Olds[w][tid][i];
    }
    const float inv = 1.0f / lv;
#pragma unroll
    for (int i = 0; i < 8; ++i) o[i] *= inv;
    float at[8];
#pragma unroll
    for (int i = 0; i < 8; ++i) {
      float a = ws[O_BCOMB + i];
#pragma unroll
      for (int d = 0; d < 8; ++d) a = fmaf(o[d], ws[O_WCOMB + d * 8 + i], a);
      at[i] = a;
    }
    float xv[8];
    loadx8(x, mytok, isf, xv);
    float z[8];
#pragma unroll
    for (int i = 0; i < 8; ++i) z[i] = xv[i] + at[i];
    float y[8];
    layernorm8(z, ws + O_G1, ws + O_BE1, y);
#pragma unroll
    for (int i = 0; i < 8; ++i) Hlds[tid][i] = y[i];
    float qin2[8];
#pragma unroll
    for (int i = 0; i < 8; ++i) {
      float a = ws[O_BPREF + i];
#pragma unroll
      for (int d = 0; d < 8; ++d) a = fmaf(y[d], ws[O_WPREF + d * 8 + i], a);
      qin2[i] = a;
    }
    float qfv[8];
    qproj(qin2, ws + O_THF, qfv);
    Qflds[tid * 4 + 0] = (unsigned)f2bf(qfv[0]) | ((unsigned)f2bf(qfv[1]) << 16);
    Qflds[tid * 4 + 1] = (unsigned)f2bf(qfv[2]) | ((unsigned)f2bf(qfv[3]) << 16);
    Qflds[tid * 4 + 2] = (unsigned)f2bf(qfv[4]) | ((unsigned)f2bf(qfv[5]) << 16);
    Qflds[tid * 4 + 3] = (unsigned)f2bf(qfv[6]) | ((unsigned)f2bf(qfv[7]) << 16);
  }
  __syncthreads();

  // ---- phase 2: FFN (wave wv owns j-range [wv*512, +512), 2 token-frags) ----
  bf16x8 qfb0 = (bf16x8)(short)0, qfb1 = qfb0;
  if (g == 0) {
    const bf16x8* qp = reinterpret_cast<const bf16x8*>(Qflds) + c;
    qfb0 = qp[0]; qfb1 = qp[16];
  } else if (g == 1) {
    qfb0[0] = (short)0x3F80; qfb1[0] = (short)0x3F80;
  }

  const bf16x8* w1a = reinterpret_cast<const bf16x8*>(ws + O_W1A) + l;
  const bf16x8* w2b = reinterpret_cast<const bf16x8*>(ws + O_W2B) + l;
  f32x4 acc0 = zero, acc1 = zero;

  bf16x8 W10 = w1a[(wv * 32 + 0) * 64], W11 = w1a[(wv * 32 + 1) * 64];
  bf16x8 W12 = w1a[(wv * 32 + 2) * 64], W13 = w1a[(wv * 32 + 3) * 64];
  bf16x8 W20 = w2b[(wv * 16 + 0) * 64], W21 = w2b[(wv * 16 + 1) * 64];

  for (int jt = 0; jt < 8; ++jt) {
    bf16x8 nW10, nW11, nW12, nW13, nW20, nW21;
    if (jt < 7) {
      const int Tb = wv * 32 + (jt + 1) * 4;
      const int Wb = wv * 16 + (jt + 1) * 2;
      nW10 = w1a[(Tb + 0) * 64]; nW11 = w1a[(Tb + 1) * 64];
      nW12 = w1a[(Tb + 2) * 64]; nW13 = w1a[(Tb + 3) * 64];
      nW20 = w2b[(Wb + 0) * 64]; nW21 = w2b[(Wb + 1) * 64];
    }
#define FFN_TOK(QF, ACC)                                                        \
    {                                                                           \
      f32x4 p0 = __builtin_amdgcn_mfma_f32_16x16x32_bf16(W10, QF, zero, 0,0,0); \
      f32x4 p1 = __builtin_amdgcn_mfma_f32_16x16x32_bf16(W11, QF, zero, 0,0,0); \
      f32x4 p2 = __builtin_amdgcn_mfma_f32_16x16x32_bf16(W12, QF, zero, 0,0,0); \
      f32x4 p3 = __builtin_amdgcn_mfma_f32_16x16x32_bf16(W13, QF, zero, 0,0,0); \
      union { unsigned u[4]; bf16x8 v; } A0, A1;                                \
      A0.u[0] = pk2(fmaxf(p0[0], 0.f), fmaxf(p0[1], 0.f));                      \
      A0.u[1] = pk2(fmaxf(p0[2], 0.f), fmaxf(p0[3], 0.f));                      \
      A0.u[2] = pk2(fmaxf(p1[0], 0.f), fmaxf(p1[1], 0.f));                      \
      A0.u[3] = pk2(fmaxf(p1[2], 0.f), fmaxf(p1[3], 0.f));                      \
      A1.u[0] = pk2(fmaxf(p2[0], 0.f), fmaxf(p2[1], 0.f));                      \
      A1.u[1] = pk2(fmaxf(p2[2], 0.f), fmaxf(p2[3], 0.f));                      \
      A1.u[2] = pk2(fmaxf(p3[0], 0.f), fmaxf(p3[1], 0.f));                      \
      A1.u[3] = pk2(fmaxf(p3[2], 0.f), fmaxf(p3[3], 0.f));                      \
      ACC = __builtin_amdgcn_mfma_f32_16x16x32_bf16(A0.v, W20, ACC, 0, 0, 0);   \
      ACC = __builtin_amdgcn_mfma_f32_16x16x32_bf16(A1.v, W21, ACC, 0, 0, 0);   \
    }
    FFN_TOK(qfb0, acc0)
    FFN_TOK(qfb1, acc1)
#undef FFN_TOK
    if (jt < 7) {
      W10 = nW10; W11 = nW11; W12 = nW12; W13 = nW13;
      W20 = nW20; W21 = nW21;
    }
  }

  if (c < 8) {
#pragma unroll
    for (int r = 0; r < 4; ++r) {
      Olds[wv][ 0 + 4 * g + r][c] = acc0[r];
      Olds[wv][16 + 4 * g + r][c] = acc1[r];
    }
  }
  __syncthreads();

  // ---- epilogue 2: reduce, b2, residual, LN2 -> out ----
  if (tid < 32) {
    const int tok = tokbase + tid;
    float f[8];
#pragma unroll
    for (int d = 0; d < 8; ++d) {
      float s = ws[O_B2 + d];
#pragma unroll
      for (int w = 0; w < 8; ++w) s += Olds[w][tid][d];
      f[d] = s;
    }
    float z[8];
#pragma unroll
    for (int d = 0; d < 8; ++d) z[d] = Hlds[tid][d] + f[d];
    float y[8];
    layernorm8(z, ws + O_G2, ws + O_BE2, y);
    if (isf) {
      float4* op = reinterpret_cast<float4*>((float*)out + tok * 8);
      op[0] = make_float4(y[0], y[1], y[2], y[3]);
      op[1] = make_float4(y[4], y[5], y[6], y[7]);
    } else {
      uint4 o;
      o.x = (unsigned)f2bf(y[0]) | ((unsigned)f2bf(y[1]) << 16);
      o.y = (unsigned)f2bf(y[2]) | ((unsigned)f2bf(y[3]) << 16);
      o.z = (unsigned)f2bf(y[4]) | ((unsigned)f2bf(y[5]) << 16);
      o.w = (unsigned)f2bf(y[6]) | ((unsigned)f2bf(y[7]) << 16);
      *reinterpret_cast<uint4*>((unsigned short*)out + tok * 8) = o;
    }
  }
}

__global__ __launch_bounds__(512) void attn_ffn_entry(const void* __restrict__ x,
                                                      const float* __restrict__ ws,
                                                      void* __restrict__ out) {
  const int isf = detect_f32_wave(x);
  attn_ffn_body(x, ws, out, isf);
}

// ---- scalar fallbacks (proven round-2 path, ws-too-small case) ----
__global__ __launch_bounds__(256) void attn_ln1(const float* __restrict__ ws,
                                                float* __restrict__ hout) {
  __shared__ float Kt[512 * 8];
  __shared__ float Vt[512 * 8];
  __shared__ float plds[8 * 32 * 9];
  const int tid = threadIdx.x;
  const int batch = blockIdx.x >> 6;
  const int chunk = blockIdx.x & 63;
  const int qlocal = tid & 31;
  const int part = tid >> 5;
  const int tok = batch * SS + chunk * 32 + qlocal;

  float qs[8];
  {
    const float* xp = ws + O_X + tok * 8;
    float qin[8];
#pragma unroll
    for (int i = 0; i < 8; ++i) {
      float a = ws[O_BPRE + i];
#pragma unroll
      for (int d = 0; d < 8; ++d) a = fmaf(xp[d], ws[O_WPRE + d * 8 + i], a);
      qin[i] = a;
    }
    float qv[8];
    qproj(qin, ws + O_THQ, qv);
#pragma unroll
    for (int i = 0; i < 8; ++i) qs[i] = qv[i] * 0.510120927f;
  }

  float ll = 0.f;
  float acc[8];
#pragma unroll
  for (int i = 0; i < 8; ++i) acc[i] = 0.f;

  for (int t = 0; t < 4; ++t) {
    const float4* Kg = reinterpret_cast<const float4*>(ws + O_K + (batch * SS + t * 512) * 8);
    const float4* Vg = reinterpret_cast<const float4*>(ws + O_V + (batch * SS + t * 512) * 8);
    float4* Kt4 = reinterpret_cast<float4*>(Kt);
    float4* Vt4 = reinterpret_cast<float4*>(Vt);
#pragma unroll
    for (int i = 0; i < 4; ++i) {
      Kt4[i * 256 + tid] = Kg[i * 256 + tid];
      Vt4[i * 256 + tid] = Vg[i * 256 + tid];
    }
    __syncthreads();
    const float* Kp = Kt + part * 64 * 8;
    const float* Vp = Vt + part * 64 * 8;
#pragma unroll 2
    for (int k = 0; k < 64; ++k) {
      float4 ka = *reinterpret_cast<const float4*>(Kp + k * 8);
      float4 kb = *reinterpret_cast<const float4*>(Kp + k * 8 + 4);
      float s = ((qs[0] * ka.x + qs[1] * ka.y) + (qs[2] * ka.z + qs[3] * ka.w)) +
                ((qs[4] * kb.x + qs[5] * kb.y) + (qs[6] * kb.z + qs[7] * kb.w));
      float p = __builtin_amdgcn_exp2f(s);
      ll += p;
      float4 va = *reinterpret_cast<const float4*>(Vp + k * 8);
      float4 vb = *reinterpret_cast<const float4*>(Vp + k * 8 + 4);
      acc[0] = fmaf(p, va.x, acc[0]);
      acc[1] = fmaf(p, va.y, acc[1]);
      acc[2] = fmaf(p, va.z, acc[2]);
      acc[3] = fmaf(p, va.w, acc[3]);
      acc[4] = fmaf(p, vb.x, acc[4]);
      acc[5] = fmaf(p, vb.y, acc[5]);
      acc[6] = fmaf(p, vb.z, acc[6]);
      acc[7] = fmaf(p, vb.w, acc[7]);
    }
    __syncthreads();
  }

  float* pp = plds + (part * 32 + qlocal) * 9;
#pragma unroll
  for (int i = 0; i < 8; ++i) pp[i] = acc[i];
  pp[8] = ll;
  __syncthreads();

  if (tid < 32) {
    float o[8];
    float ls = 0.f;
#pragma unroll
    for (int i = 0; i < 8; ++i) o[i] = 0.f;
#pragma unroll
    for (int pr = 0; pr < 8; ++pr) {
      const float* q = plds + (pr * 32 + tid) * 9;
#pragma unroll
      for (int i = 0; i < 8; ++i) o[i] += q[i];
      ls += q[8];
    }
    const float inv = 1.0f / ls;
#pragma unroll
    for (int i = 0; i < 8; ++i) o[i] *= inv;
    const int mytok = batch * SS + chunk * 32 + tid;
    float at[8];
#pragma unroll
    for (int i = 0; i < 8; ++i) {
      float a = ws[O_BCOMB + i];
#pragma unroll
      for (int d = 0; d < 8; ++d) a = fmaf(o[d], ws[O_WCOMB + d * 8 + i], a);
      at[i] = a;
    }
    const float* xp = ws + O_X + mytok * 8;
    float z[8];
#pragma unroll
    for (int i = 0; i < 8; ++i) z[i] = xp[i] + at[i];
    float y[8];
    layernorm8(z, ws + O_G1, ws + O_BE1, y);
    float4* hp = reinterpret_cast<float4*>(hout + mytok * 8);
    hp[0] = make_float4(y[0], y[1], y[2], y[3]);
    hp[1] = make_float4(y[4], y[5], y[6], y[7]);
  }
}

__global__ __launch_bounds__(256) void ffn_ln2(const float* __restrict__ ws,
                                               void* __restrict__ out) {
  __shared__ float plds[4 * 64 * 8];
  const int tid = threadIdx.x;
  const int tok = blockIdx.x * 64 + (tid & 63);
  const int part = __builtin_amdgcn_readfirstlane(tid >> 6);

  const float* hp = ws + O_H + tok * 8;
  float4 h0 = *reinterpret_cast<const float4*>(hp);
  float4 h1 = *reinterpret_cast<const float4*>(hp + 4);
  float hv[8] = {h0.x, h0.y, h0.z, h0.w, h1.x, h1.y, h1.z, h1.w};

  float qin[8];
#pragma unroll
  for (int i = 0; i < 8; ++i) {
    float a = ws[O_BPREF + i];
#pragma unroll
    for (int d = 0; d < 8; ++d) a = fmaf(hv[d], ws[O_WPREF + d * 8 + i], a);
    qin[i] = a;
  }
  float qf[8];
  qproj(qin, ws + O_THF, qf);

  float acc[8];
#pragma unroll
  for (int i = 0; i < 8; ++i) acc[i] = 0.f;
  const float* w1t = ws + O_W1T + part * 1024 * 8;
  const float* b1f = ws + O_B1F + part * 1024;
  const float* w2f = ws + O_W2F + part * 1024 * 8;
#pragma unroll 4
  for (int j = 0; j < 1024; ++j) {
    float hj = b1f[j];
    const float* wa = w1t + j * 8;
#pragma unroll
    for (int d = 0; d < 8; ++d) hj = fmaf(qf[d], wa[d], hj);
    hj = fmaxf(hj, 0.f);
    const float* wb = w2f + j * 8;
#pragma unroll
    for (int d = 0; d < 8; ++d) acc[d] = fmaf(hj, wb[d], acc[d]);
  }

  float* pp = plds + part * 512 + (tid & 63) * 8;
#pragma unroll
  for (int d = 0; d < 8; ++d) pp[d] = acc[d];
  __syncthreads();

  if (tid < 64) {
    const int isf = (int)ws[O_FLAG];
    float f[8];
#pragma unroll
    for (int d = 0; d < 8; ++d)
      f[d] = ws[O_B2 + d] + plds[tid * 8 + d] + plds[512 + tid * 8 + d] +
             plds[1024 + tid * 8 + d] + plds[1536 + tid * 8 + d];
    float z[8];
#pragma unroll
    for (int d = 0; d < 8; ++d) z[d] = hv[d] + f[d];
    float y[8];
    layernorm8(z, ws + O_G2, ws + O_BE2, y);
    const int otok = blockIdx.x * 64 + tid;
    if (isf) {
      float4* op = reinterpret_cast<float4*>((float*)out + otok * 8);
      op[0] = make_float4(y[0], y[1], y[2], y[3]);
      op[1] = make_float4(y[4], y[5], y[6], y[7]);
    } else {
      uint4 o;
      o.x = (unsigned)f2bf(y[0]) | ((unsigned)f2bf(y[1]) << 16);
      o.y = (unsigned)f2bf(y[2]) | ((unsigned)f2bf(y[3]) << 16);
      o.z = (unsigned)f2bf(y[4]) | ((unsigned)f2bf(y[5]) << 16);
      o.w = (unsigned)f2bf(y[6]) | ((unsigned)f2bf(y[7]) << 16);
      *reinterpret_cast<uint4*>((unsigned short*)out + otok * 8) = o;
    }
  }
}

extern "C" void kernel_launch(void* const* d_in, const int* in_sizes, int n_in,
                              void* d_out, int out_size, void* d_ws, size_t ws_size,
                              hipStream_t stream) {
  float* ws = (float*)d_ws;
  const int mfma_ok = (ws_size >= WS_MFMA);

  prep_all<<<dim3(177), dim3(256), 0, stream>>>(
      d_in[0], d_in[1], d_in[2], d_in[3], d_in[4], d_in[5], d_in[6],
      d_in[7], d_in[8], d_in[9], d_in[10], d_in[11], d_in[12], d_in[13],
      d_in[14], d_in[15], d_in[16], d_in[17], d_in[18], ws, mfma_ok);

  if (mfma_ok) {
    attn_ffn_entry<<<dim3(512), dim3(512), 0, stream>>>(d_in[0], ws, d_out);
  } else {
    attn_ln1<<<dim3(512), dim3(256), 0, stream>>>(ws, ws + O_H);
    ffn_ln2<<<dim3(256), dim3(256), 0, stream>>>(ws, d_out);
  }
}

// Round 13
// 33.286 us; speedup vs baseline: 1.0142x; 1.0142x over previous
//
#include <hip/hip_runtime.h>
#include <hip/hip_bf16.h>

#define BB 8
#define SS 2048
#define EE 8
#define FF 4096
#define NTOK (BB*SS)

using bf16x8 = __attribute__((ext_vector_type(8))) short;
using f32x4  = __attribute__((ext_vector_type(4))) float;

// ---- workspace layout (float offsets) ----
constexpr int O_FLAG  = 0;
constexpr int O_WPRE  = 8;      // 64
constexpr int O_BPRE  = 72;     // 8
constexpr int O_THQ   = 80;     // 8
constexpr int O_THK   = 88;     // 8
constexpr int O_THV   = 96;     // 8
constexpr int O_WCOMB = 104;    // 64
constexpr int O_BCOMB = 168;    // 8
constexpr int O_G1    = 176;    // 8
constexpr int O_BE1   = 184;    // 8
constexpr int O_G2    = 192;    // 8
constexpr int O_BE2   = 200;    // 8
constexpr int O_WPREF = 208;    // 64
constexpr int O_BPREF = 272;    // 8
constexpr int O_THF   = 280;    // 8
constexpr int O_B2    = 288;    // 8
constexpr int O_W1T   = 512;             // fallback
constexpr int O_B1F   = O_W1T + FF*8;
constexpr int O_W2F   = O_B1F + FF;
constexpr int O_X     = O_W2F + FF*8;    // fallback path only
constexpr int O_K     = O_X + NTOK*EE;   // fallback attn
constexpr int O_V     = O_K + NTOK*EE;   // fallback attn
constexpr int O_H     = O_V + NTOK*EE;   // fallback
constexpr int O_P     = O_H + NTOK*EE;   // unused (layout stability)
constexpr int O_QFB   = O_P + 8*NTOK*EE; // unused on fused path
constexpr int O_W1A   = O_QFB + NTOK*4;  // 65536 f
constexpr int O_W2B   = O_W1A + 65536;   // 32768 f
constexpr int O_QB    = O_W2B + 32768;   // NTOK*4
constexpr int O_KB    = O_QB + NTOK*4;   // NTOK*4
constexpr int O_VTB   = O_KB + NTOK*4;   // 65536 f
constexpr size_t WS_MFMA = (size_t)(O_VTB + 65536) * 4;

__device__ __forceinline__ float b2f(unsigned short u) {
  return __uint_as_float(((unsigned)u) << 16);
}

__device__ __forceinline__ unsigned short f2bf(float f) {
  unsigned u = __float_as_uint(f);
  unsigned r = (u + 0x7fffu + ((u >> 16) & 1u)) >> 16;
  return (unsigned short)r;
}

// pack two f32 -> bf16x2 (a at low half = element 0)
__device__ __forceinline__ unsigned pk2(float a, float b) {
  unsigned ua = __float_as_uint(a) + 0x8000u;
  unsigned ub = __float_as_uint(b) + 0x8000u;
  return __builtin_amdgcn_perm(ub, ua, 0x07060302u);
}

__device__ __forceinline__ float loadin(const void* p, int i, int isf) {
  if (isf) return reinterpret_cast<const float*>(p)[i];
  return b2f(reinterpret_cast<const unsigned short*>(p)[i]);
}

// vectorized 8-element input row load (token granularity)
__device__ __forceinline__ void loadx8(const void* x, int tok, int isf, float* xv) {
  if (isf) {
    float4 a = reinterpret_cast<const float4*>(x)[tok * 2];
    float4 b = reinterpret_cast<const float4*>(x)[tok * 2 + 1];
    xv[0] = a.x; xv[1] = a.y; xv[2] = a.z; xv[3] = a.w;
    xv[4] = b.x; xv[5] = b.y; xv[6] = b.z; xv[7] = b.w;
  } else {
    uint4 u = reinterpret_cast<const uint4*>(x)[tok];
    xv[0] = __uint_as_float(u.x << 16); xv[1] = __uint_as_float(u.x & 0xffff0000u);
    xv[2] = __uint_as_float(u.y << 16); xv[3] = __uint_as_float(u.y & 0xffff0000u);
    xv[4] = __uint_as_float(u.z << 16); xv[5] = __uint_as_float(u.z & 0xffff0000u);
    xv[6] = __uint_as_float(u.w << 16); xv[7] = __uint_as_float(u.w & 0xffff0000u);
  }
}

// Wave-cooperative dtype sniff (see earlier rounds); P(misdetect)~2e-17.
__device__ __forceinline__ int detect_f32_wave(const void* x) {
  unsigned u = reinterpret_cast<const unsigned*>(x)[threadIdx.x & 63];
  float v = b2f((unsigned short)u);
  int bad = !(fabsf(v) <= 1e4f);
  return __ballot(bad) != 0ull;
}

// <Z_k>: c = cos(z+theta); out_k = prod_{i<=k} c_i (k>=1); out_0 = prod_{i=1..7} c_i
__device__ __forceinline__ void qproj(const float* qin, const float* th, float* out) {
  float c[8];
#pragma unroll
  for (int i = 0; i < 8; ++i) c[i] = __cosf(qin[i] + th[i]);
  float p = c[1];
#pragma unroll
  for (int i = 2; i < 8; ++i) p *= c[i];
  out[0] = p;
  float r = c[0];
#pragma unroll
  for (int i = 1; i < 8; ++i) { r *= c[i]; out[i] = r; }
}

__device__ __forceinline__ void layernorm8(const float* z, const float* g, const float* b, float* y) {
  float m = 0.f;
#pragma unroll
  for (int i = 0; i < 8; ++i) m += z[i];
  m *= 0.125f;
  float v = 0.f;
#pragma unroll
  for (int i = 0; i < 8; ++i) { float d = z[i] - m; v += d * d; }
  v *= 0.125f;
  float rs = rsqrtf(v + 1e-5f);
#pragma unroll
  for (int i = 0; i < 8; ++i) y[i] = (z[i] - m) * rs * g[i] + b[i];
}

// ==== prep helpers (proven) ====

__device__ __forceinline__ void prep_token_mfma(
    int tok, const void* x, const void* w_pre, const void* b_pre,
    const void* th_q, const void* th_k, const void* th_v,
    float* __restrict__ ws, int isf) {
  float xv[8];
  loadx8(x, tok, isf, xv);
  float qin[8];
#pragma unroll
  for (int i = 0; i < 8; ++i) {
    float a = loadin(b_pre, i, isf);
#pragma unroll
    for (int d = 0; d < 8; ++d) a = fmaf(xv[d], loadin(w_pre, d * 8 + i, isf), a);
    qin[i] = a;
  }
  float thq[8], thk[8], thv[8];
#pragma unroll
  for (int i = 0; i < 8; ++i) {
    thq[i] = loadin(th_q, i, isf);
    thk[i] = loadin(th_k, i, isf);
    thv[i] = loadin(th_v, i, isf);
  }
  float qv[8], kv[8], vv[8];
  qproj(qin, thq, qv);
  qproj(qin, thk, kv);
  qproj(qin, thv, vv);
  const float sc = 0.510120927f;  // log2(e)/sqrt(8)
  uint4 uq, uk;
  uq.x = (unsigned)f2bf(qv[0] * sc) | ((unsigned)f2bf(qv[1] * sc) << 16);
  uq.y = (unsigned)f2bf(qv[2] * sc) | ((unsigned)f2bf(qv[3] * sc) << 16);
  uq.z = (unsigned)f2bf(qv[4] * sc) | ((unsigned)f2bf(qv[5] * sc) << 16);
  uq.w = (unsigned)f2bf(qv[6] * sc) | ((unsigned)f2bf(qv[7] * sc) << 16);
  uk.x = (unsigned)f2bf(kv[0]) | ((unsigned)f2bf(kv[1]) << 16);
  uk.y = (unsigned)f2bf(kv[2]) | ((unsigned)f2bf(kv[3]) << 16);
  uk.z = (unsigned)f2bf(kv[4]) | ((unsigned)f2bf(kv[5]) << 16);
  uk.w = (unsigned)f2bf(kv[6]) | ((unsigned)f2bf(kv[7]) << 16);
  reinterpret_cast<uint4*>(ws + O_QB)[tok] = uq;
  reinterpret_cast<uint4*>(ws + O_KB)[tok] = uk;
  unsigned short* vtb = reinterpret_cast<unsigned short*>(ws + O_VTB);
#pragma unroll
  for (int i = 0; i < 8; ++i) vtb[i * NTOK + tok] = f2bf(vv[i]);
}

__device__ __forceinline__ void prep_w1a(int idx, const void* w1, const void* b1,
                                         float* __restrict__ ws, int isf) {
  const int T = idx >> 6, l = idx & 63, c = l & 15, g = l >> 4;
  const int j = T * 16 + c;
  float f[8];
#pragma unroll
  for (int e = 0; e < 8; ++e) f[e] = 0.f;
  if (g == 0) {
#pragma unroll
    for (int e = 0; e < 8; ++e) f[e] = loadin(w1, e * FF + j, isf);
  } else if (g == 1) {
    f[0] = loadin(b1, j, isf);
  }
  uint4 u;
  u.x = (unsigned)f2bf(f[0]) | ((unsigned)f2bf(f[1]) << 16);
  u.y = (unsigned)f2bf(f[2]) | ((unsigned)f2bf(f[3]) << 16);
  u.z = (unsigned)f2bf(f[4]) | ((unsigned)f2bf(f[5]) << 16);
  u.w = (unsigned)f2bf(f[6]) | ((unsigned)f2bf(f[7]) << 16);
  reinterpret_cast<uint4*>(ws + O_W1A)[idx] = u;
}

__device__ __forceinline__ void prep_w2b(int idx2, const void* w2,
                                         float* __restrict__ ws, int isf) {
  const int W = idx2 >> 6, l = idx2 & 63, i = l & 15, g = l >> 4;
  float f[8];
#pragma unroll
  for (int e = 0; e < 8; ++e) f[e] = 0.f;
  if (i < 8) {
#pragma unroll
    for (int e = 0; e < 8; ++e) {
      const int j = W * 32 + 16 * (e >> 2) + 4 * g + (e & 3);  // pi-permutation
      f[e] = loadin(w2, j * 8 + i, isf);
    }
  }
  uint4 u;
  u.x = (unsigned)f2bf(f[0]) | ((unsigned)f2bf(f[1]) << 16);
  u.y = (unsigned)f2bf(f[2]) | ((unsigned)f2bf(f[3]) << 16);
  u.z = (unsigned)f2bf(f[4]) | ((unsigned)f2bf(f[5]) << 16);
  u.w = (unsigned)f2bf(f[6]) | ((unsigned)f2bf(f[7]) << 16);
  reinterpret_cast<uint4*>(ws + O_W2B)[idx2] = u;
}

// ---- kernel A (fused prep): grid 177 x 256 (proven) ----
__global__ __launch_bounds__(256) void prep_all(
    const void* x, const void* w_pre, const void* b_pre, const void* th_q,
    const void* th_k, const void* th_v, const void* w_comb, const void* b_comb,
    const void* g1, const void* be1, const void* g2, const void* be2,
    const void* w_pre_f, const void* b_pre_f, const void* th_f,
    const void* w1, const void* b1, const void* w2, const void* b2,
    float* __restrict__ ws, int mfma_ok) {
  const int bid = blockIdx.x, tid = threadIdx.x;
  const int isf = detect_f32_wave(x);
  if (bid < 64) {
    const int tok = bid * 256 + tid;
    if (mfma_ok) {
      prep_token_mfma(tok, x, w_pre, b_pre, th_q, th_k, th_v, ws, isf);
    } else {
      float xv[8];
      loadx8(x, tok, isf, xv);
      float qin[8];
#pragma unroll
      for (int i = 0; i < 8; ++i) {
        float a = loadin(b_pre, i, isf);
#pragma unroll
        for (int d = 0; d < 8; ++d) a = fmaf(xv[d], loadin(w_pre, d * 8 + i, isf), a);
        qin[i] = a;
      }
      float thq[8], thk[8], thv[8];
#pragma unroll
      for (int i = 0; i < 8; ++i) {
        thq[i] = loadin(th_q, i, isf);
        thk[i] = loadin(th_k, i, isf);
        thv[i] = loadin(th_v, i, isf);
      }
      float qv[8], kv[8], vv[8];
      qproj(qin, thq, qv);
      qproj(qin, thk, kv);
      qproj(qin, thv, vv);
      float4* xp = reinterpret_cast<float4*>(ws + O_X + tok * 8);
      xp[0] = make_float4(xv[0], xv[1], xv[2], xv[3]);
      xp[1] = make_float4(xv[4], xv[5], xv[6], xv[7]);
      float4* kp = reinterpret_cast<float4*>(ws + O_K + tok * 8);
      float4* vp = reinterpret_cast<float4*>(ws + O_V + tok * 8);
      kp[0] = make_float4(kv[0], kv[1], kv[2], kv[3]);
      kp[1] = make_float4(kv[4], kv[5], kv[6], kv[7]);
      vp[0] = make_float4(vv[0], vv[1], vv[2], vv[3]);
      vp[1] = make_float4(vv[4], vv[5], vv[6], vv[7]);
    }
  } else if (bid < 128) {
    if (!mfma_ok) return;
    prep_w1a((bid - 64) * 256 + tid, w1, b1, ws, isf);
  } else if (bid < 160) {
    if (!mfma_ok) return;
    prep_w2b((bid - 128) * 256 + tid, w2, ws, isf);
  } else if (bid == 160) {
    if (tid < 64) {
      ws[O_WPRE + tid]  = loadin(w_pre, tid, isf);
      ws[O_WCOMB + tid] = loadin(w_comb, tid, isf);
      ws[O_WPREF + tid] = loadin(w_pre_f, tid, isf);
    }
    if (tid < 8) {
      ws[O_BPRE + tid]  = loadin(b_pre, tid, isf);
      ws[O_THQ + tid]   = loadin(th_q, tid, isf);
      ws[O_THK + tid]   = loadin(th_k, tid, isf);
      ws[O_THV + tid]   = loadin(th_v, tid, isf);
      ws[O_BCOMB + tid] = loadin(b_comb, tid, isf);
      ws[O_G1 + tid]    = loadin(g1, tid, isf);
      ws[O_BE1 + tid]   = loadin(be1, tid, isf);
      ws[O_G2 + tid]    = loadin(g2, tid, isf);
      ws[O_BE2 + tid]   = loadin(be2, tid, isf);
      ws[O_BPREF + tid] = loadin(b_pre_f, tid, isf);
      ws[O_THF + tid]   = loadin(th_f, tid, isf);
      ws[O_B2 + tid]    = loadin(b2, tid, isf);
    }
    if (tid == 0) ws[O_FLAG] = (float)isf;
  } else {
    if (mfma_ok) return;
    const int j = (bid - 161) * 256 + tid;
    ws[O_B1F + j] = loadin(b1, j, isf);
#pragma unroll
    for (int i = 0; i < 8; ++i) {
      ws[O_W1T + j * 8 + i] = loadin(w1, i * FF + j, isf);
      ws[O_W2F + j * 8 + i] = loadin(w2, j * 8 + i, isf);
    }
  }
}

// ==== fused attn+ffn body: 64 tokens/block, 16 waves, grid 256 x 1024 ====
// 16 waves/CU (VGPR=88 occupancy cap) AND minimal weight traffic (256 blocks).
// Wave wv: attn keys [batch*SS + wv*128, +128) (4 windows); FFN j [wv*256,+256).
// No manual K/V prefetch (R12 lesson: it hurt).
__device__ __forceinline__ void attn_ffn_body(const void* __restrict__ x,
                                              const float* __restrict__ ws,
                                              void* __restrict__ out, int isf) {
  __shared__ float Olds[16][64][8];    // 32 KB
  __shared__ float Llds[16][64];       // 4 KB
  __shared__ float Hlds[64][8];        // 2 KB
  __shared__ unsigned Qflds[64 * 4];   // 1 KB
  const int tid = threadIdx.x;
  const int wv = tid >> 6, l = tid & 63;
  const int c = l & 15, g = l >> 4;
  const int tokbase = blockIdx.x * 64;
  const int batch = blockIdx.x >> 5;   // 32 blocks per batch

  const bf16x8 zerov = (bf16x8)(short)0;
  const f32x4 zero = {0.f, 0.f, 0.f, 0.f};

  // ---- phase 1: attention ----
  bf16x8 qb0 = zerov, qb1 = zerov, qb2 = zerov, qb3 = zerov;
  if (g == 0) {
    const bf16x8* qp = reinterpret_cast<const bf16x8*>(ws + O_QB) + tokbase + c;
    qb0 = qp[0]; qb1 = qp[16]; qb2 = qp[32]; qb3 = qp[48];
  }
  const bf16x8* Kb = reinterpret_cast<const bf16x8*>(ws + O_KB);
  const unsigned short* vtb = reinterpret_cast<const unsigned short*>(ws + O_VTB);

  f32x4 oacc0 = zero, oacc1 = zero, oacc2 = zero, oacc3 = zero;
  float ls0 = 0.f, ls1 = 0.f, ls2 = 0.f, ls3 = 0.f;
  const int kbase = batch * SS + wv * 128;

  for (int w = 0; w < 4; ++w) {
    const int kt = kbase + w * 32;
    bf16x8 kf0 = zerov, kf1 = zerov;
    if (g == 0) {
      kf0 = Kb[kt + c];
      kf1 = Kb[kt + 16 + c];
    }
    union { uint2 u[2]; bf16x8 v; } VF;
    VF.u[0] = make_uint2(0u, 0u);
    VF.u[1] = make_uint2(0u, 0u);
    if (c < 8) {
      VF.u[0] = *reinterpret_cast<const uint2*>(vtb + c * NTOK + kt + 4 * g);
      VF.u[1] = *reinterpret_cast<const uint2*>(vtb + c * NTOK + kt + 16 + 4 * g);
    }
#define ATT_QT(QB, OACC, LS)                                                     \
    {                                                                            \
      f32x4 s0 = __builtin_amdgcn_mfma_f32_16x16x32_bf16(kf0, QB, zero, 0,0,0);  \
      f32x4 s1 = __builtin_amdgcn_mfma_f32_16x16x32_bf16(kf1, QB, zero, 0,0,0);  \
      float p0[4], p1[4];                                                        \
      _Pragma("unroll")                                                          \
      for (int r = 0; r < 4; ++r) {                                              \
        p0[r] = __builtin_amdgcn_exp2f(s0[r]);                                   \
        p1[r] = __builtin_amdgcn_exp2f(s1[r]);                                   \
        LS += p0[r] + p1[r];                                                     \
      }                                                                          \
      union { unsigned u[4]; bf16x8 v; } PA;                                     \
      PA.u[0] = pk2(p0[0], p0[1]);                                               \
      PA.u[1] = pk2(p0[2], p0[3]);                                               \
      PA.u[2] = pk2(p1[0], p1[1]);                                               \
      PA.u[3] = pk2(p1[2], p1[3]);                                               \
      OACC = __builtin_amdgcn_mfma_f32_16x16x32_bf16(PA.v, VF.v, OACC, 0, 0, 0); \
    }
    ATT_QT(qb0, oacc0, ls0)
    ATT_QT(qb1, oacc1, ls1)
    ATT_QT(qb2, oacc2, ls2)
    ATT_QT(qb3, oacc3, ls3)
#undef ATT_QT
  }

  ls0 += __shfl_xor(ls0, 16); ls0 += __shfl_xor(ls0, 32);
  ls1 += __shfl_xor(ls1, 16); ls1 += __shfl_xor(ls1, 32);
  ls2 += __shfl_xor(ls2, 16); ls2 += __shfl_xor(ls2, 32);
  ls3 += __shfl_xor(ls3, 16); ls3 += __shfl_xor(ls3, 32);
  if (l < 16) {
    Llds[wv][l]      = ls0;
    Llds[wv][16 + l] = ls1;
    Llds[wv][32 + l] = ls2;
    Llds[wv][48 + l] = ls3;
  }
  if (c < 8) {
#pragma unroll
    for (int r = 0; r < 4; ++r) {
      Olds[wv][ 0 + 4 * g + r][c] = oacc0[r];
      Olds[wv][16 + 4 * g + r][c] = oacc1[r];
      Olds[wv][32 + 4 * g + r][c] = oacc2[r];
      Olds[wv][48 + 4 * g + r][c] = oacc3[r];
    }
  }
  __syncthreads();

  // ---- epilogue 1: combine, w_comb, residual, LN1, QF -> LDS ----
  if (tid < 64) {
    const int mytok = tokbase + tid;
    float lv = 0.f;
    float o[8];
#pragma unroll
    for (int i = 0; i < 8; ++i) o[i] = 0.f;
#pragma unroll
    for (int w = 0; w < 16; ++w) {
      lv += Llds[w][tid];
#pragma unroll
      for (int i = 0; i < 8; ++i) o[i] += Olds[w][tid][i];
    }
    const float inv = 1.0f / lv;
#pragma unroll
    for (int i = 0; i < 8; ++i) o[i] *= inv;
    float at[8];
#pragma unroll
    for (int i = 0; i < 8; ++i) {
      float a = ws[O_BCOMB + i];
#pragma unroll
      for (int d = 0; d < 8; ++d) a = fmaf(o[d], ws[O_WCOMB + d * 8 + i], a);
      at[i] = a;
    }
    float xv[8];
    loadx8(x, mytok, isf, xv);
    float z[8];
#pragma unroll
    for (int i = 0; i < 8; ++i) z[i] = xv[i] + at[i];
    float y[8];
    layernorm8(z, ws + O_G1, ws + O_BE1, y);
#pragma unroll
    for (int i = 0; i < 8; ++i) Hlds[tid][i] = y[i];
    float qin2[8];
#pragma unroll
    for (int i = 0; i < 8; ++i) {
      float a = ws[O_BPREF + i];
#pragma unroll
      for (int d = 0; d < 8; ++d) a = fmaf(y[d], ws[O_WPREF + d * 8 + i], a);
      qin2[i] = a;
    }
    float qfv[8];
    qproj(qin2, ws + O_THF, qfv);
    Qflds[tid * 4 + 0] = (unsigned)f2bf(qfv[0]) | ((unsigned)f2bf(qfv[1]) << 16);
    Qflds[tid * 4 + 1] = (unsigned)f2bf(qfv[2]) | ((unsigned)f2bf(qfv[3]) << 16);
    Qflds[tid * 4 + 2] = (unsigned)f2bf(qfv[4]) | ((unsigned)f2bf(qfv[5]) << 16);
    Qflds[tid * 4 + 3] = (unsigned)f2bf(qfv[6]) | ((unsigned)f2bf(qfv[7]) << 16);
  }
  __syncthreads();

  // ---- phase 2: FFN (wave wv owns j-range [wv*256, +256), 4 token-frags) ----
  bf16x8 qfb0 = (bf16x8)(short)0, qfb1 = qfb0, qfb2 = qfb0, qfb3 = qfb0;
  if (g == 0) {
    const bf16x8* qp = reinterpret_cast<const bf16x8*>(Qflds) + c;
    qfb0 = qp[0]; qfb1 = qp[16]; qfb2 = qp[32]; qfb3 = qp[48];
  } else if (g == 1) {
    qfb0[0] = (short)0x3F80; qfb1[0] = (short)0x3F80;
    qfb2[0] = (short)0x3F80; qfb3[0] = (short)0x3F80;
  }

  const bf16x8* w1a = reinterpret_cast<const bf16x8*>(ws + O_W1A) + l;
  const bf16x8* w2b = reinterpret_cast<const bf16x8*>(ws + O_W2B) + l;
  f32x4 acc0 = zero, acc1 = zero, acc2 = zero, acc3 = zero;

  // wave j-range: Tb = wv*16 + jt*4 (16-j tiles), Wb = wv*8 + jt*2 (32-j windows)
  bf16x8 W10 = w1a[(wv * 16 + 0) * 64], W11 = w1a[(wv * 16 + 1) * 64];
  bf16x8 W12 = w1a[(wv * 16 + 2) * 64], W13 = w1a[(wv * 16 + 3) * 64];
  bf16x8 W20 = w2b[(wv * 8 + 0) * 64],  W21 = w2b[(wv * 8 + 1) * 64];

  for (int jt = 0; jt < 4; ++jt) {
    bf16x8 nW10, nW11, nW12, nW13, nW20, nW21;
    if (jt < 3) {
      const int Tb = wv * 16 + (jt + 1) * 4;
      const int Wb = wv * 8 + (jt + 1) * 2;
      nW10 = w1a[(Tb + 0) * 64]; nW11 = w1a[(Tb + 1) * 64];
      nW12 = w1a[(Tb + 2) * 64]; nW13 = w1a[(Tb + 3) * 64];
      nW20 = w2b[(Wb + 0) * 64]; nW21 = w2b[(Wb + 1) * 64];
    }
#define FFN_TOK(QF, ACC)                                                        \
    {                                                                           \
      f32x4 p0 = __builtin_amdgcn_mfma_f32_16x16x32_bf16(W10, QF, zero, 0,0,0); \
      f32x4 p1 = __builtin_amdgcn_mfma_f32_16x16x32_bf16(W11, QF, zero, 0,0,0); \
      f32x4 p2 = __builtin_amdgcn_mfma_f32_16x16x32_bf16(W12, QF, zero, 0,0,0); \
      f32x4 p3 = __builtin_amdgcn_mfma_f32_16x16x32_bf16(W13, QF, zero, 0,0,0); \
      union { unsigned u[4]; bf16x8 v; } A0, A1;                                \
      A0.u[0] = pk2(fmaxf(p0[0], 0.f), fmaxf(p0[1], 0.f));                      \
      A0.u[1] = pk2(fmaxf(p0[2], 0.f), fmaxf(p0[3], 0.f));                      \
      A0.u[2] = pk2(fmaxf(p1[0], 0.f), fmaxf(p1[1], 0.f));                      \
      A0.u[3] = pk2(fmaxf(p1[2], 0.f), fmaxf(p1[3], 0.f));                      \
      A1.u[0] = pk2(fmaxf(p2[0], 0.f), fmaxf(p2[1], 0.f));                      \
      A1.u[1] = pk2(fmaxf(p2[2], 0.f), fmaxf(p2[3], 0.f));                      \
      A1.u[2] = pk2(fmaxf(p3[0], 0.f), fmaxf(p3[1], 0.f));                      \
      A1.u[3] = pk2(fmaxf(p3[2], 0.f), fmaxf(p3[3], 0.f));                      \
      ACC = __builtin_amdgcn_mfma_f32_16x16x32_bf16(A0.v, W20, ACC, 0, 0, 0);   \
      ACC = __builtin_amdgcn_mfma_f32_16x16x32_bf16(A1.v, W21, ACC, 0, 0, 0);   \
    }
    FFN_TOK(qfb0, acc0)
    FFN_TOK(qfb1, acc1)
    FFN_TOK(qfb2, acc2)
    FFN_TOK(qfb3, acc3)
#undef FFN_TOK
    if (jt < 3) {
      W10 = nW10; W11 = nW11; W12 = nW12; W13 = nW13;
      W20 = nW20; W21 = nW21;
    }
  }

  if (c < 8) {
#pragma unroll
    for (int r = 0; r < 4; ++r) {
      Olds[wv][ 0 + 4 * g + r][c] = acc0[r];
      Olds[wv][16 + 4 * g + r][c] = acc1[r];
      Olds[wv][32 + 4 * g + r][c] = acc2[r];
      Olds[wv][48 + 4 * g + r][c] = acc3[r];
    }
  }
  __syncthreads();

  // ---- epilogue 2: reduce, b2, residual, LN2 -> out ----
  if (tid < 64) {
    const int tok = tokbase + tid;
    float f[8];
#pragma unroll
    for (int d = 0; d < 8; ++d) {
      float s = ws[O_B2 + d];
#pragma unroll
      for (int w = 0; w < 16; ++w) s += Olds[w][tid][d];
      f[d] = s;
    }
    float z[8];
#pragma unroll
    for (int d = 0; d < 8; ++d) z[d] = Hlds[tid][d] + f[d];
    float y[8];
    layernorm8(z, ws + O_G2, ws + O_BE2, y);
    if (isf) {
      float4* op = reinterpret_cast<float4*>((float*)out + tok * 8);
      op[0] = make_float4(y[0], y[1], y[2], y[3]);
      op[1] = make_float4(y[4], y[5], y[6], y[7]);
    } else {
      uint4 o;
      o.x = (unsigned)f2bf(y[0]) | ((unsigned)f2bf(y[1]) << 16);
      o.y = (unsigned)f2bf(y[2]) | ((unsigned)f2bf(y[3]) << 16);
      o.z = (unsigned)f2bf(y[4]) | ((unsigned)f2bf(y[5]) << 16);
      o.w = (unsigned)f2bf(y[6]) | ((unsigned)f2bf(y[7]) << 16);
      *reinterpret_cast<uint4*>((unsigned short*)out + tok * 8) = o;
    }
  }
}

__global__ __launch_bounds__(1024) void attn_ffn_entry(const void* __restrict__ x,
                                                       const float* __restrict__ ws,
                                                       void* __restrict__ out) {
  const int isf = detect_f32_wave(x);
  attn_ffn_body(x, ws, out, isf);
}

// ---- scalar fallbacks (proven round-2 path, ws-too-small case) ----
__global__ __launch_bounds__(256) void attn_ln1(const float* __restrict__ ws,
                                                float* __restrict__ hout) {
  __shared__ float Kt[512 * 8];
  __shared__ float Vt[512 * 8];
  __shared__ float plds[8 * 32 * 9];
  const int tid = threadIdx.x;
  const int batch = blockIdx.x >> 6;
  const int chunk = blockIdx.x & 63;
  const int qlocal = tid & 31;
  const int part = tid >> 5;
  const int tok = batch * SS + chunk * 32 + qlocal;

  float qs[8];
  {
    const float* xp = ws + O_X + tok * 8;
    float qin[8];
#pragma unroll
    for (int i = 0; i < 8; ++i) {
      float a = ws[O_BPRE + i];
#pragma unroll
      for (int d = 0; d < 8; ++d) a = fmaf(xp[d], ws[O_WPRE + d * 8 + i], a);
      qin[i] = a;
    }
    float qv[8];
    qproj(qin, ws + O_THQ, qv);
#pragma unroll
    for (int i = 0; i < 8; ++i) qs[i] = qv[i] * 0.510120927f;
  }

  float ll = 0.f;
  float acc[8];
#pragma unroll
  for (int i = 0; i < 8; ++i) acc[i] = 0.f;

  for (int t = 0; t < 4; ++t) {
    const float4* Kg = reinterpret_cast<const float4*>(ws + O_K + (batch * SS + t * 512) * 8);
    const float4* Vg = reinterpret_cast<const float4*>(ws + O_V + (batch * SS + t * 512) * 8);
    float4* Kt4 = reinterpret_cast<float4*>(Kt);
    float4* Vt4 = reinterpret_cast<float4*>(Vt);
#pragma unroll
    for (int i = 0; i < 4; ++i) {
      Kt4[i * 256 + tid] = Kg[i * 256 + tid];
      Vt4[i * 256 + tid] = Vg[i * 256 + tid];
    }
    __syncthreads();
    const float* Kp = Kt + part * 64 * 8;
    const float* Vp = Vt + part * 64 * 8;
#pragma unroll 2
    for (int k = 0; k < 64; ++k) {
      float4 ka = *reinterpret_cast<const float4*>(Kp + k * 8);
      float4 kb = *reinterpret_cast<const float4*>(Kp + k * 8 + 4);
      float s = ((qs[0] * ka.x + qs[1] * ka.y) + (qs[2] * ka.z + qs[3] * ka.w)) +
                ((qs[4] * kb.x + qs[5] * kb.y) + (qs[6] * kb.z + qs[7] * kb.w));
      float p = __builtin_amdgcn_exp2f(s);
      ll += p;
      float4 va = *reinterpret_cast<const float4*>(Vp + k * 8);
      float4 vb = *reinterpret_cast<const float4*>(Vp + k * 8 + 4);
      acc[0] = fmaf(p, va.x, acc[0]);
      acc[1] = fmaf(p, va.y, acc[1]);
      acc[2] = fmaf(p, va.z, acc[2]);
      acc[3] = fmaf(p, va.w, acc[3]);
      acc[4] = fmaf(p, vb.x, acc[4]);
      acc[5] = fmaf(p, vb.y, acc[5]);
      acc[6] = fmaf(p, vb.z, acc[6]);
      acc[7] = fmaf(p, vb.w, acc[7]);
    }
    __syncthreads();
  }

  float* pp = plds + (part * 32 + qlocal) * 9;
#pragma unroll
  for (int i = 0; i < 8; ++i) pp[i] = acc[i];
  pp[8] = ll;
  __syncthreads();

  if (tid < 32) {
    float o[8];
    float ls = 0.f;
#pragma unroll
    for (int i = 0; i < 8; ++i) o[i] = 0.f;
#pragma unroll
    for (int pr = 0; pr < 8; ++pr) {
      const float* q = plds + (pr * 32 + tid) * 9;
#pragma unroll
      for (int i = 0; i < 8; ++i) o[i] += q[i];
      ls += q[8];
    }
    const float inv = 1.0f / ls;
#pragma unroll
    for (int i = 0; i < 8; ++i) o[i] *= inv;
    const int mytok = batch * SS + chunk * 32 + tid;
    float at[8];
#pragma unroll
    for (int i = 0; i < 8; ++i) {
      float a = ws[O_BCOMB + i];
#pragma unroll
      for (int d = 0; d < 8; ++d) a = fmaf(o[d], ws[O_WCOMB + d * 8 + i], a);
      at[i] = a;
    }
    const float* xp = ws + O_X + mytok * 8;
    float z[8];
#pragma unroll
    for (int i = 0; i < 8; ++i) z[i] = xp[i] + at[i];
    float y[8];
    layernorm8(z, ws + O_G1, ws + O_BE1, y);
    float4* hp = reinterpret_cast<float4*>(hout + mytok * 8);
    hp[0] = make_float4(y[0], y[1], y[2], y[3]);
    hp[1] = make_float4(y[4], y[5], y[6], y[7]);
  }
}

__global__ __launch_bounds__(256) void ffn_ln2(const float* __restrict__ ws,
                                               void* __restrict__ out) {
  __shared__ float plds[4 * 64 * 8];
  const int tid = threadIdx.x;
  const int tok = blockIdx.x * 64 + (tid & 63);
  const int part = __builtin_amdgcn_readfirstlane(tid >> 6);

  const float* hp = ws + O_H + tok * 8;
  float4 h0 = *reinterpret_cast<const float4*>(hp);
  float4 h1 = *reinterpret_cast<const float4*>(hp + 4);
  float hv[8] = {h0.x, h0.y, h0.z, h0.w, h1.x, h1.y, h1.z, h1.w};

  float qin[8];
#pragma unroll
  for (int i = 0; i < 8; ++i) {
    float a = ws[O_BPREF + i];
#pragma unroll
    for (int d = 0; d < 8; ++d) a = fmaf(hv[d], ws[O_WPREF + d * 8 + i], a);
    qin[i] = a;
  }
  float qf[8];
  qproj(qin, ws + O_THF, qf);

  float acc[8];
#pragma unroll
  for (int i = 0; i < 8; ++i) acc[i] = 0.f;
  const float* w1t = ws + O_W1T + part * 1024 * 8;
  const float* b1f = ws + O_B1F + part * 1024;
  const float* w2f = ws + O_W2F + part * 1024 * 8;
#pragma unroll 4
  for (int j = 0; j < 1024; ++j) {
    float hj = b1f[j];
    const float* wa = w1t + j * 8;
#pragma unroll
    for (int d = 0; d < 8; ++d) hj = fmaf(qf[d], wa[d], hj);
    hj = fmaxf(hj, 0.f);
    const float* wb = w2f + j * 8;
#pragma unroll
    for (int d = 0; d < 8; ++d) acc[d] = fmaf(hj, wb[d], acc[d]);
  }

  float* pp = plds + part * 512 + (tid & 63) * 8;
#pragma unroll
  for (int d = 0; d < 8; ++d) pp[d] = acc[d];
  __syncthreads();

  if (tid < 64) {
    const int isf = (int)ws[O_FLAG];
    float f[8];
#pragma unroll
    for (int d = 0; d < 8; ++d)
      f[d] = ws[O_B2 + d] + plds[tid * 8 + d] + plds[512 + tid * 8 + d] +
             plds[1024 + tid * 8 + d] + plds[1536 + tid * 8 + d];
    float z[8];
#pragma unroll
    for (int d = 0; d < 8; ++d) z[d] = hv[d] + f[d];
    float y[8];
    layernorm8(z, ws + O_G2, ws + O_BE2, y);
    const int otok = blockIdx.x * 64 + tid;
    if (isf) {
      float4* op = reinterpret_cast<float4*>((float*)out + otok * 8);
      op[0] = make_float4(y[0], y[1], y[2], y[3]);
      op[1] = make_float4(y[4], y[5], y[6], y[7]);
    } else {
      uint4 o;
      o.x = (unsigned)f2bf(y[0]) | ((unsigned)f2bf(y[1]) << 16);
      o.y = (unsigned)f2bf(y[2]) | ((unsigned)f2bf(y[3]) << 16);
      o.z = (unsigned)f2bf(y[4]) | ((unsigned)f2bf(y[5]) << 16);
      o.w = (unsigned)f2bf(y[6]) | ((unsigned)f2bf(y[7]) << 16);
      *reinterpret_cast<uint4*>((unsigned short*)out + otok * 8) = o;
    }
  }
}

extern "C" void kernel_launch(void* const* d_in, const int* in_sizes, int n_in,
                              void* d_out, int out_size, void* d_ws, size_t ws_size,
                              hipStream_t stream) {
  float* ws = (float*)d_ws;
  const int mfma_ok = (ws_size >= WS_MFMA);

  prep_all<<<dim3(177), dim3(256), 0, stream>>>(
      d_in[0], d_in[1], d_in[2], d_in[3], d_in[4], d_in[5], d_in[6],
      d_in[7], d_in[8], d_in[9], d_in[10], d_in[11], d_in[12], d_in[13],
      d_in[14], d_in[15], d_in[16], d_in[17], d_in[18], ws, mfma_ok);

  if (mfma_ok) {
    attn_ffn_entry<<<dim3(256), dim3(1024), 0, stream>>>(d_in[0], ws, d_out);
  } else {
    attn_ln1<<<dim3(512), dim3(256), 0, stream>>>(ws, ws + O_H);
    ffn_ln2<<<dim3(256), dim3(256), 0, stream>>>(ws, d_out);
  }
}

// Round 14
// 33.230 us; speedup vs baseline: 1.0160x; 1.0017x over previous
//
#include <hip/hip_runtime.h>
#include <hip/hip_bf16.h>

#define BB 8
#define SS 2048
#define EE 8
#define FF 4096
#define NTOK (BB*SS)

using bf16x8 = __attribute__((ext_vector_type(8))) short;
using f32x4  = __attribute__((ext_vector_type(4))) float;

// ---- workspace layout (float offsets) ----
constexpr int O_FLAG  = 0;
constexpr int O_WPRE  = 8;      // 64
constexpr int O_BPRE  = 72;     // 8
constexpr int O_THQ   = 80;     // 8
constexpr int O_THK   = 88;     // 8
constexpr int O_THV   = 96;     // 8
constexpr int O_WCOMB = 104;    // 64
constexpr int O_BCOMB = 168;    // 8
constexpr int O_G1    = 176;    // 8
constexpr int O_BE1   = 184;    // 8
constexpr int O_G2    = 192;    // 8
constexpr int O_BE2   = 200;    // 8
constexpr int O_WPREF = 208;    // 64
constexpr int O_BPREF = 272;    // 8
constexpr int O_THF   = 280;    // 8
constexpr int O_B2    = 288;    // 8
constexpr int O_W1T   = 512;             // fallback
constexpr int O_B1F   = O_W1T + FF*8;
constexpr int O_W2F   = O_B1F + FF;
constexpr int O_X     = O_W2F + FF*8;    // fallback path only
constexpr int O_K     = O_X + NTOK*EE;   // fallback attn
constexpr int O_V     = O_K + NTOK*EE;   // fallback attn
constexpr int O_H     = O_V + NTOK*EE;   // fallback
constexpr int O_P     = O_H + NTOK*EE;   // unused (layout stability)
constexpr int O_QFB   = O_P + 8*NTOK*EE; // unused on fused path
constexpr int O_W1A   = O_QFB + NTOK*4;  // 65536 f
constexpr int O_W2B   = O_W1A + 65536;   // 32768 f
constexpr int O_QB    = O_W2B + 32768;   // NTOK*4
constexpr int O_KB    = O_QB + NTOK*4;   // NTOK*4
constexpr int O_VTB   = O_KB + NTOK*4;   // 65536 f
constexpr size_t WS_MFMA = (size_t)(O_VTB + 65536) * 4;

__device__ __forceinline__ float b2f(unsigned short u) {
  return __uint_as_float(((unsigned)u) << 16);
}

__device__ __forceinline__ unsigned short f2bf(float f) {
  unsigned u = __float_as_uint(f);
  unsigned r = (u + 0x7fffu + ((u >> 16) & 1u)) >> 16;
  return (unsigned short)r;
}

// pack two f32 -> bf16x2 (a at low half = element 0)
__device__ __forceinline__ unsigned pk2(float a, float b) {
  unsigned ua = __float_as_uint(a) + 0x8000u;
  unsigned ub = __float_as_uint(b) + 0x8000u;
  return __builtin_amdgcn_perm(ub, ua, 0x07060302u);
}

__device__ __forceinline__ float loadin(const void* p, int i, int isf) {
  if (isf) return reinterpret_cast<const float*>(p)[i];
  return b2f(reinterpret_cast<const unsigned short*>(p)[i]);
}

// vectorized 8-element input row load (token granularity)
__device__ __forceinline__ void loadx8(const void* x, int tok, int isf, float* xv) {
  if (isf) {
    float4 a = reinterpret_cast<const float4*>(x)[tok * 2];
    float4 b = reinterpret_cast<const float4*>(x)[tok * 2 + 1];
    xv[0] = a.x; xv[1] = a.y; xv[2] = a.z; xv[3] = a.w;
    xv[4] = b.x; xv[5] = b.y; xv[6] = b.z; xv[7] = b.w;
  } else {
    uint4 u = reinterpret_cast<const uint4*>(x)[tok];
    xv[0] = __uint_as_float(u.x << 16); xv[1] = __uint_as_float(u.x & 0xffff0000u);
    xv[2] = __uint_as_float(u.y << 16); xv[3] = __uint_as_float(u.y & 0xffff0000u);
    xv[4] = __uint_as_float(u.z << 16); xv[5] = __uint_as_float(u.z & 0xffff0000u);
    xv[6] = __uint_as_float(u.w << 16); xv[7] = __uint_as_float(u.w & 0xffff0000u);
  }
}

// Wave-cooperative dtype sniff (see earlier rounds); P(misdetect)~2e-17.
__device__ __forceinline__ int detect_f32_wave(const void* x) {
  unsigned u = reinterpret_cast<const unsigned*>(x)[threadIdx.x & 63];
  float v = b2f((unsigned short)u);
  int bad = !(fabsf(v) <= 1e4f);
  return __ballot(bad) != 0ull;
}

// <Z_k>: c = cos(z+theta); out_k = prod_{i<=k} c_i (k>=1); out_0 = prod_{i=1..7} c_i
__device__ __forceinline__ void qproj(const float* qin, const float* th, float* out) {
  float c[8];
#pragma unroll
  for (int i = 0; i < 8; ++i) c[i] = __cosf(qin[i] + th[i]);
  float p = c[1];
#pragma unroll
  for (int i = 2; i < 8; ++i) p *= c[i];
  out[0] = p;
  float r = c[0];
#pragma unroll
  for (int i = 1; i < 8; ++i) { r *= c[i]; out[i] = r; }
}

__device__ __forceinline__ void layernorm8(const float* z, const float* g, const float* b, float* y) {
  float m = 0.f;
#pragma unroll
  for (int i = 0; i < 8; ++i) m += z[i];
  m *= 0.125f;
  float v = 0.f;
#pragma unroll
  for (int i = 0; i < 8; ++i) { float d = z[i] - m; v += d * d; }
  v *= 0.125f;
  float rs = rsqrtf(v + 1e-5f);
#pragma unroll
  for (int i = 0; i < 8; ++i) y[i] = (z[i] - m) * rs * g[i] + b[i];
}

// ==== prep helpers (proven) ====

__device__ __forceinline__ void prep_token_mfma(
    int tok, const void* x, const void* w_pre, const void* b_pre,
    const void* th_q, const void* th_k, const void* th_v,
    float* __restrict__ ws, int isf) {
  float xv[8];
  loadx8(x, tok, isf, xv);
  float qin[8];
#pragma unroll
  for (int i = 0; i < 8; ++i) {
    float a = loadin(b_pre, i, isf);
#pragma unroll
    for (int d = 0; d < 8; ++d) a = fmaf(xv[d], loadin(w_pre, d * 8 + i, isf), a);
    qin[i] = a;
  }
  float thq[8], thk[8], thv[8];
#pragma unroll
  for (int i = 0; i < 8; ++i) {
    thq[i] = loadin(th_q, i, isf);
    thk[i] = loadin(th_k, i, isf);
    thv[i] = loadin(th_v, i, isf);
  }
  float qv[8], kv[8], vv[8];
  qproj(qin, thq, qv);
  qproj(qin, thk, kv);
  qproj(qin, thv, vv);
  const float sc = 0.510120927f;  // log2(e)/sqrt(8)
  uint4 uq, uk;
  uq.x = (unsigned)f2bf(qv[0] * sc) | ((unsigned)f2bf(qv[1] * sc) << 16);
  uq.y = (unsigned)f2bf(qv[2] * sc) | ((unsigned)f2bf(qv[3] * sc) << 16);
  uq.z = (unsigned)f2bf(qv[4] * sc) | ((unsigned)f2bf(qv[5] * sc) << 16);
  uq.w = (unsigned)f2bf(qv[6] * sc) | ((unsigned)f2bf(qv[7] * sc) << 16);
  uk.x = (unsigned)f2bf(kv[0]) | ((unsigned)f2bf(kv[1]) << 16);
  uk.y = (unsigned)f2bf(kv[2]) | ((unsigned)f2bf(kv[3]) << 16);
  uk.z = (unsigned)f2bf(kv[4]) | ((unsigned)f2bf(kv[5]) << 16);
  uk.w = (unsigned)f2bf(kv[6]) | ((unsigned)f2bf(kv[7]) << 16);
  reinterpret_cast<uint4*>(ws + O_QB)[tok] = uq;
  reinterpret_cast<uint4*>(ws + O_KB)[tok] = uk;
  unsigned short* vtb = reinterpret_cast<unsigned short*>(ws + O_VTB);
#pragma unroll
  for (int i = 0; i < 8; ++i) vtb[i * NTOK + tok] = f2bf(vv[i]);
}

__device__ __forceinline__ void prep_w1a(int idx, const void* w1, const void* b1,
                                         float* __restrict__ ws, int isf) {
  const int T = idx >> 6, l = idx & 63, c = l & 15, g = l >> 4;
  const int j = T * 16 + c;
  float f[8];
#pragma unroll
  for (int e = 0; e < 8; ++e) f[e] = 0.f;
  if (g == 0) {
#pragma unroll
    for (int e = 0; e < 8; ++e) f[e] = loadin(w1, e * FF + j, isf);
  } else if (g == 1) {
    f[0] = loadin(b1, j, isf);
  }
  uint4 u;
  u.x = (unsigned)f2bf(f[0]) | ((unsigned)f2bf(f[1]) << 16);
  u.y = (unsigned)f2bf(f[2]) | ((unsigned)f2bf(f[3]) << 16);
  u.z = (unsigned)f2bf(f[4]) | ((unsigned)f2bf(f[5]) << 16);
  u.w = (unsigned)f2bf(f[6]) | ((unsigned)f2bf(f[7]) << 16);
  reinterpret_cast<uint4*>(ws + O_W1A)[idx] = u;
}

__device__ __forceinline__ void prep_w2b(int idx2, const void* w2,
                                         float* __restrict__ ws, int isf) {
  const int W = idx2 >> 6, l = idx2 & 63, i = l & 15, g = l >> 4;
  float f[8];
#pragma unroll
  for (int e = 0; e < 8; ++e) f[e] = 0.f;
  if (i < 8) {
#pragma unroll
    for (int e = 0; e < 8; ++e) {
      const int j = W * 32 + 16 * (e >> 2) + 4 * g + (e & 3);  // pi-permutation
      f[e] = loadin(w2, j * 8 + i, isf);
    }
  }
  uint4 u;
  u.x = (unsigned)f2bf(f[0]) | ((unsigned)f2bf(f[1]) << 16);
  u.y = (unsigned)f2bf(f[2]) | ((unsigned)f2bf(f[3]) << 16);
  u.z = (unsigned)f2bf(f[4]) | ((unsigned)f2bf(f[5]) << 16);
  u.w = (unsigned)f2bf(f[6]) | ((unsigned)f2bf(f[7]) << 16);
  reinterpret_cast<uint4*>(ws + O_W2B)[idx2] = u;
}

// ---- kernel A (fused prep): grid 177 x 256 (proven) ----
__global__ __launch_bounds__(256) void prep_all(
    const void* x, const void* w_pre, const void* b_pre, const void* th_q,
    const void* th_k, const void* th_v, const void* w_comb, const void* b_comb,
    const void* g1, const void* be1, const void* g2, const void* be2,
    const void* w_pre_f, const void* b_pre_f, const void* th_f,
    const void* w1, const void* b1, const void* w2, const void* b2,
    float* __restrict__ ws, int mfma_ok) {
  const int bid = blockIdx.x, tid = threadIdx.x;
  const int isf = detect_f32_wave(x);
  if (bid < 64) {
    const int tok = bid * 256 + tid;
    if (mfma_ok) {
      prep_token_mfma(tok, x, w_pre, b_pre, th_q, th_k, th_v, ws, isf);
    } else {
      float xv[8];
      loadx8(x, tok, isf, xv);
      float qin[8];
#pragma unroll
      for (int i = 0; i < 8; ++i) {
        float a = loadin(b_pre, i, isf);
#pragma unroll
        for (int d = 0; d < 8; ++d) a = fmaf(xv[d], loadin(w_pre, d * 8 + i, isf), a);
        qin[i] = a;
      }
      float thq[8], thk[8], thv[8];
#pragma unroll
      for (int i = 0; i < 8; ++i) {
        thq[i] = loadin(th_q, i, isf);
        thk[i] = loadin(th_k, i, isf);
        thv[i] = loadin(th_v, i, isf);
      }
      float qv[8], kv[8], vv[8];
      qproj(qin, thq, qv);
      qproj(qin, thk, kv);
      qproj(qin, thv, vv);
      float4* xp = reinterpret_cast<float4*>(ws + O_X + tok * 8);
      xp[0] = make_float4(xv[0], xv[1], xv[2], xv[3]);
      xp[1] = make_float4(xv[4], xv[5], xv[6], xv[7]);
      float4* kp = reinterpret_cast<float4*>(ws + O_K + tok * 8);
      float4* vp = reinterpret_cast<float4*>(ws + O_V + tok * 8);
      kp[0] = make_float4(kv[0], kv[1], kv[2], kv[3]);
      kp[1] = make_float4(kv[4], kv[5], kv[6], kv[7]);
      vp[0] = make_float4(vv[0], vv[1], vv[2], vv[3]);
      vp[1] = make_float4(vv[4], vv[5], vv[6], vv[7]);
    }
  } else if (bid < 128) {
    if (!mfma_ok) return;
    prep_w1a((bid - 64) * 256 + tid, w1, b1, ws, isf);
  } else if (bid < 160) {
    if (!mfma_ok) return;
    prep_w2b((bid - 128) * 256 + tid, w2, ws, isf);
  } else if (bid == 160) {
    if (tid < 64) {
      ws[O_WPRE + tid]  = loadin(w_pre, tid, isf);
      ws[O_WCOMB + tid] = loadin(w_comb, tid, isf);
      ws[O_WPREF + tid] = loadin(w_pre_f, tid, isf);
    }
    if (tid < 8) {
      ws[O_BPRE + tid]  = loadin(b_pre, tid, isf);
      ws[O_THQ + tid]   = loadin(th_q, tid, isf);
      ws[O_THK + tid]   = loadin(th_k, tid, isf);
      ws[O_THV + tid]   = loadin(th_v, tid, isf);
      ws[O_BCOMB + tid] = loadin(b_comb, tid, isf);
      ws[O_G1 + tid]    = loadin(g1, tid, isf);
      ws[O_BE1 + tid]   = loadin(be1, tid, isf);
      ws[O_G2 + tid]    = loadin(g2, tid, isf);
      ws[O_BE2 + tid]   = loadin(be2, tid, isf);
      ws[O_BPREF + tid] = loadin(b_pre_f, tid, isf);
      ws[O_THF + tid]   = loadin(th_f, tid, isf);
      ws[O_B2 + tid]    = loadin(b2, tid, isf);
    }
    if (tid == 0) ws[O_FLAG] = (float)isf;
  } else {
    if (mfma_ok) return;
    const int j = (bid - 161) * 256 + tid;
    ws[O_B1F + j] = loadin(b1, j, isf);
#pragma unroll
    for (int i = 0; i < 8; ++i) {
      ws[O_W1T + j * 8 + i] = loadin(w1, i * FF + j, isf);
      ws[O_W2F + j * 8 + i] = loadin(w2, j * 8 + i, isf);
    }
  }
}

// ==== fused attn+ffn body: 64 tokens/block, 16 waves, grid 256 x 1024 ====
// 16 waves/CU AND minimal weight traffic (256 blocks). launch_bounds(1024,4)
// -> VGPR budget 128 (body needs ~88): NO spills (R13 lesson: default clamp
// to 64 VGPR caused 12.5 MB of scratch traffic).
__device__ __forceinline__ void attn_ffn_body(const void* __restrict__ x,
                                              const float* __restrict__ ws,
                                              void* __restrict__ out, int isf) {
  __shared__ float Olds[16][64][8];    // 32 KB
  __shared__ float Llds[16][64];       // 4 KB
  __shared__ float Hlds[64][8];        // 2 KB
  __shared__ unsigned Qflds[64 * 4];   // 1 KB
  const int tid = threadIdx.x;
  const int wv = tid >> 6, l = tid & 63;
  const int c = l & 15, g = l >> 4;
  const int tokbase = blockIdx.x * 64;
  const int batch = blockIdx.x >> 5;   // 32 blocks per batch

  const bf16x8 zerov = (bf16x8)(short)0;
  const f32x4 zero = {0.f, 0.f, 0.f, 0.f};

  // ---- phase 1: attention ----
  bf16x8 qb0 = zerov, qb1 = zerov, qb2 = zerov, qb3 = zerov;
  if (g == 0) {
    const bf16x8* qp = reinterpret_cast<const bf16x8*>(ws + O_QB) + tokbase + c;
    qb0 = qp[0]; qb1 = qp[16]; qb2 = qp[32]; qb3 = qp[48];
  }
  const bf16x8* Kb = reinterpret_cast<const bf16x8*>(ws + O_KB);
  const unsigned short* vtb = reinterpret_cast<const unsigned short*>(ws + O_VTB);

  f32x4 oacc0 = zero, oacc1 = zero, oacc2 = zero, oacc3 = zero;
  float ls0 = 0.f, ls1 = 0.f, ls2 = 0.f, ls3 = 0.f;
  const int kbase = batch * SS + wv * 128;

  for (int w = 0; w < 4; ++w) {
    const int kt = kbase + w * 32;
    bf16x8 kf0 = zerov, kf1 = zerov;
    if (g == 0) {
      kf0 = Kb[kt + c];
      kf1 = Kb[kt + 16 + c];
    }
    union { uint2 u[2]; bf16x8 v; } VF;
    VF.u[0] = make_uint2(0u, 0u);
    VF.u[1] = make_uint2(0u, 0u);
    if (c < 8) {
      VF.u[0] = *reinterpret_cast<const uint2*>(vtb + c * NTOK + kt + 4 * g);
      VF.u[1] = *reinterpret_cast<const uint2*>(vtb + c * NTOK + kt + 16 + 4 * g);
    }
#define ATT_QT(QB, OACC, LS)                                                     \
    {                                                                            \
      f32x4 s0 = __builtin_amdgcn_mfma_f32_16x16x32_bf16(kf0, QB, zero, 0,0,0);  \
      f32x4 s1 = __builtin_amdgcn_mfma_f32_16x16x32_bf16(kf1, QB, zero, 0,0,0);  \
      float p0[4], p1[4];                                                        \
      _Pragma("unroll")                                                          \
      for (int r = 0; r < 4; ++r) {                                              \
        p0[r] = __builtin_amdgcn_exp2f(s0[r]);                                   \
        p1[r] = __builtin_amdgcn_exp2f(s1[r]);                                   \
        LS += p0[r] + p1[r];                                                     \
      }                                                                          \
      union { unsigned u[4]; bf16x8 v; } PA;                                     \
      PA.u[0] = pk2(p0[0], p0[1]);                                               \
      PA.u[1] = pk2(p0[2], p0[3]);                                               \
      PA.u[2] = pk2(p1[0], p1[1]);                                               \
      PA.u[3] = pk2(p1[2], p1[3]);                                               \
      OACC = __builtin_amdgcn_mfma_f32_16x16x32_bf16(PA.v, VF.v, OACC, 0, 0, 0); \
    }
    ATT_QT(qb0, oacc0, ls0)
    ATT_QT(qb1, oacc1, ls1)
    ATT_QT(qb2, oacc2, ls2)
    ATT_QT(qb3, oacc3, ls3)
#undef ATT_QT
  }

  ls0 += __shfl_xor(ls0, 16); ls0 += __shfl_xor(ls0, 32);
  ls1 += __shfl_xor(ls1, 16); ls1 += __shfl_xor(ls1, 32);
  ls2 += __shfl_xor(ls2, 16); ls2 += __shfl_xor(ls2, 32);
  ls3 += __shfl_xor(ls3, 16); ls3 += __shfl_xor(ls3, 32);
  if (l < 16) {
    Llds[wv][l]      = ls0;
    Llds[wv][16 + l] = ls1;
    Llds[wv][32 + l] = ls2;
    Llds[wv][48 + l] = ls3;
  }
  if (c < 8) {
#pragma unroll
    for (int r = 0; r < 4; ++r) {
      Olds[wv][ 0 + 4 * g + r][c] = oacc0[r];
      Olds[wv][16 + 4 * g + r][c] = oacc1[r];
      Olds[wv][32 + 4 * g + r][c] = oacc2[r];
      Olds[wv][48 + 4 * g + r][c] = oacc3[r];
    }
  }
  __syncthreads();

  // ---- epilogue 1: combine, w_comb, residual, LN1, QF -> LDS ----
  if (tid < 64) {
    const int mytok = tokbase + tid;
    float lv = 0.f;
    float o[8];
#pragma unroll
    for (int i = 0; i < 8; ++i) o[i] = 0.f;
#pragma unroll
    for (int w = 0; w < 16; ++w) {
      lv += Llds[w][tid];
#pragma unroll
      for (int i = 0; i < 8; ++i) o[i] += Olds[w][tid][i];
    }
    const float inv = 1.0f / lv;
#pragma unroll
    for (int i = 0; i < 8; ++i) o[i] *= inv;
    float at[8];
#pragma unroll
    for (int i = 0; i < 8; ++i) {
      float a = ws[O_BCOMB + i];
#pragma unroll
      for (int d = 0; d < 8; ++d) a = fmaf(o[d], ws[O_WCOMB + d * 8 + i], a);
      at[i] = a;
    }
    float xv[8];
    loadx8(x, mytok, isf, xv);
    float z[8];
#pragma unroll
    for (int i = 0; i < 8; ++i) z[i] = xv[i] + at[i];
    float y[8];
    layernorm8(z, ws + O_G1, ws + O_BE1, y);
#pragma unroll
    for (int i = 0; i < 8; ++i) Hlds[tid][i] = y[i];
    float qin2[8];
#pragma unroll
    for (int i = 0; i < 8; ++i) {
      float a = ws[O_BPREF + i];
#pragma unroll
      for (int d = 0; d < 8; ++d) a = fmaf(y[d], ws[O_WPREF + d * 8 + i], a);
      qin2[i] = a;
    }
    float qfv[8];
    qproj(qin2, ws + O_THF, qfv);
    Qflds[tid * 4 + 0] = (unsigned)f2bf(qfv[0]) | ((unsigned)f2bf(qfv[1]) << 16);
    Qflds[tid * 4 + 1] = (unsigned)f2bf(qfv[2]) | ((unsigned)f2bf(qfv[3]) << 16);
    Qflds[tid * 4 + 2] = (unsigned)f2bf(qfv[4]) | ((unsigned)f2bf(qfv[5]) << 16);
    Qflds[tid * 4 + 3] = (unsigned)f2bf(qfv[6]) | ((unsigned)f2bf(qfv[7]) << 16);
  }
  __syncthreads();

  // ---- phase 2: FFN (wave wv owns j-range [wv*256, +256), 4 token-frags) ----
  bf16x8 qfb0 = (bf16x8)(short)0, qfb1 = qfb0, qfb2 = qfb0, qfb3 = qfb0;
  if (g == 0) {
    const bf16x8* qp = reinterpret_cast<const bf16x8*>(Qflds) + c;
    qfb0 = qp[0]; qfb1 = qp[16]; qfb2 = qp[32]; qfb3 = qp[48];
  } else if (g == 1) {
    qfb0[0] = (short)0x3F80; qfb1[0] = (short)0x3F80;
    qfb2[0] = (short)0x3F80; qfb3[0] = (short)0x3F80;
  }

  const bf16x8* w1a = reinterpret_cast<const bf16x8*>(ws + O_W1A) + l;
  const bf16x8* w2b = reinterpret_cast<const bf16x8*>(ws + O_W2B) + l;
  f32x4 acc0 = zero, acc1 = zero, acc2 = zero, acc3 = zero;

  // wave j-range: Tb = wv*16 + jt*4 (16-j tiles), Wb = wv*8 + jt*2 (32-j windows)
  bf16x8 W10 = w1a[(wv * 16 + 0) * 64], W11 = w1a[(wv * 16 + 1) * 64];
  bf16x8 W12 = w1a[(wv * 16 + 2) * 64], W13 = w1a[(wv * 16 + 3) * 64];
  bf16x8 W20 = w2b[(wv * 8 + 0) * 64],  W21 = w2b[(wv * 8 + 1) * 64];

  for (int jt = 0; jt < 4; ++jt) {
    bf16x8 nW10, nW11, nW12, nW13, nW20, nW21;
    if (jt < 3) {
      const int Tb = wv * 16 + (jt + 1) * 4;
      const int Wb = wv * 8 + (jt + 1) * 2;
      nW10 = w1a[(Tb + 0) * 64]; nW11 = w1a[(Tb + 1) * 64];
      nW12 = w1a[(Tb + 2) * 64]; nW13 = w1a[(Tb + 3) * 64];
      nW20 = w2b[(Wb + 0) * 64]; nW21 = w2b[(Wb + 1) * 64];
    }
#define FFN_TOK(QF, ACC)                                                        \
    {                                                                           \
      f32x4 p0 = __builtin_amdgcn_mfma_f32_16x16x32_bf16(W10, QF, zero, 0,0,0); \
      f32x4 p1 = __builtin_amdgcn_mfma_f32_16x16x32_bf16(W11, QF, zero, 0,0,0); \
      f32x4 p2 = __builtin_amdgcn_mfma_f32_16x16x32_bf16(W12, QF, zero, 0,0,0); \
      f32x4 p3 = __builtin_amdgcn_mfma_f32_16x16x32_bf16(W13, QF, zero, 0,0,0); \
      union { unsigned u[4]; bf16x8 v; } A0, A1;                                \
      A0.u[0] = pk2(fmaxf(p0[0], 0.f), fmaxf(p0[1], 0.f));                      \
      A0.u[1] = pk2(fmaxf(p0[2], 0.f), fmaxf(p0[3], 0.f));                      \
      A0.u[2] = pk2(fmaxf(p1[0], 0.f), fmaxf(p1[1], 0.f));                      \
      A0.u[3] = pk2(fmaxf(p1[2], 0.f), fmaxf(p1[3], 0.f));                      \
      A1.u[0] = pk2(fmaxf(p2[0], 0.f), fmaxf(p2[1], 0.f));                      \
      A1.u[1] = pk2(fmaxf(p2[2], 0.f), fmaxf(p2[3], 0.f));                      \
      A1.u[2] = pk2(fmaxf(p3[0], 0.f), fmaxf(p3[1], 0.f));                      \
      A1.u[3] = pk2(fmaxf(p3[2], 0.f), fmaxf(p3[3], 0.f));                      \
      ACC = __builtin_amdgcn_mfma_f32_16x16x32_bf16(A0.v, W20, ACC, 0, 0, 0);   \
      ACC = __builtin_amdgcn_mfma_f32_16x16x32_bf16(A1.v, W21, ACC, 0, 0, 0);   \
    }
    FFN_TOK(qfb0, acc0)
    FFN_TOK(qfb1, acc1)
    FFN_TOK(qfb2, acc2)
    FFN_TOK(qfb3, acc3)
#undef FFN_TOK
    if (jt < 3) {
      W10 = nW10; W11 = nW11; W12 = nW12; W13 = nW13;
      W20 = nW20; W21 = nW21;
    }
  }

  if (c < 8) {
#pragma unroll
    for (int r = 0; r < 4; ++r) {
      Olds[wv][ 0 + 4 * g + r][c] = acc0[r];
      Olds[wv][16 + 4 * g + r][c] = acc1[r];
      Olds[wv][32 + 4 * g + r][c] = acc2[r];
      Olds[wv][48 + 4 * g + r][c] = acc3[r];
    }
  }
  __syncthreads();

  // ---- epilogue 2: reduce, b2, residual, LN2 -> out ----
  if (tid < 64) {
    const int tok = tokbase + tid;
    float f[8];
#pragma unroll
    for (int d = 0; d < 8; ++d) {
      float s = ws[O_B2 + d];
#pragma unroll
      for (int w = 0; w < 16; ++w) s += Olds[w][tid][d];
      f[d] = s;
    }
    float z[8];
#pragma unroll
    for (int d = 0; d < 8; ++d) z[d] = Hlds[tid][d] + f[d];
    float y[8];
    layernorm8(z, ws + O_G2, ws + O_BE2, y);
    if (isf) {
      float4* op = reinterpret_cast<float4*>((float*)out + tok * 8);
      op[0] = make_float4(y[0], y[1], y[2], y[3]);
      op[1] = make_float4(y[4], y[5], y[6], y[7]);
    } else {
      uint4 o;
      o.x = (unsigned)f2bf(y[0]) | ((unsigned)f2bf(y[1]) << 16);
      o.y = (unsigned)f2bf(y[2]) | ((unsigned)f2bf(y[3]) << 16);
      o.z = (unsigned)f2bf(y[4]) | ((unsigned)f2bf(y[5]) << 16);
      o.w = (unsigned)f2bf(y[6]) | ((unsigned)f2bf(y[7]) << 16);
      *reinterpret_cast<uint4*>((unsigned short*)out + tok * 8) = o;
    }
  }
}

__global__ __launch_bounds__(1024, 4) void attn_ffn_entry(const void* __restrict__ x,
                                                          const float* __restrict__ ws,
                                                          void* __restrict__ out) {
  const int isf = detect_f32_wave(x);
  attn_ffn_body(x, ws, out, isf);
}

// ---- scalar fallbacks (proven round-2 path, ws-too-small case) ----
__global__ __launch_bounds__(256) void attn_ln1(const float* __restrict__ ws,
                                                float* __restrict__ hout) {
  __shared__ float Kt[512 * 8];
  __shared__ float Vt[512 * 8];
  __shared__ float plds[8 * 32 * 9];
  const int tid = threadIdx.x;
  const int batch = blockIdx.x >> 6;
  const int chunk = blockIdx.x & 63;
  const int qlocal = tid & 31;
  const int part = tid >> 5;
  const int tok = batch * SS + chunk * 32 + qlocal;

  float qs[8];
  {
    const float* xp = ws + O_X + tok * 8;
    float qin[8];
#pragma unroll
    for (int i = 0; i < 8; ++i) {
      float a = ws[O_BPRE + i];
#pragma unroll
      for (int d = 0; d < 8; ++d) a = fmaf(xp[d], ws[O_WPRE + d * 8 + i], a);
      qin[i] = a;
    }
    float qv[8];
    qproj(qin, ws + O_THQ, qv);
#pragma unroll
    for (int i = 0; i < 8; ++i) qs[i] = qv[i] * 0.510120927f;
  }

  float ll = 0.f;
  float acc[8];
#pragma unroll
  for (int i = 0; i < 8; ++i) acc[i] = 0.f;

  for (int t = 0; t < 4; ++t) {
    const float4* Kg = reinterpret_cast<const float4*>(ws + O_K + (batch * SS + t * 512) * 8);
    const float4* Vg = reinterpret_cast<const float4*>(ws + O_V + (batch * SS + t * 512) * 8);
    float4* Kt4 = reinterpret_cast<float4*>(Kt);
    float4* Vt4 = reinterpret_cast<float4*>(Vt);
#pragma unroll
    for (int i = 0; i < 4; ++i) {
      Kt4[i * 256 + tid] = Kg[i * 256 + tid];
      Vt4[i * 256 + tid] = Vg[i * 256 + tid];
    }
    __syncthreads();
    const float* Kp = Kt + part * 64 * 8;
    const float* Vp = Vt + part * 64 * 8;
#pragma unroll 2
    for (int k = 0; k < 64; ++k) {
      float4 ka = *reinterpret_cast<const float4*>(Kp + k * 8);
      float4 kb = *reinterpret_cast<const float4*>(Kp + k * 8 + 4);
      float s = ((qs[0] * ka.x + qs[1] * ka.y) + (qs[2] * ka.z + qs[3] * ka.w)) +
                ((qs[4] * kb.x + qs[5] * kb.y) + (qs[6] * kb.z + qs[7] * kb.w));
      float p = __builtin_amdgcn_exp2f(s);
      ll += p;
      float4 va = *reinterpret_cast<const float4*>(Vp + k * 8);
      float4 vb = *reinterpret_cast<const float4*>(Vp + k * 8 + 4);
      acc[0] = fmaf(p, va.x, acc[0]);
      acc[1] = fmaf(p, va.y, acc[1]);
      acc[2] = fmaf(p, va.z, acc[2]);
      acc[3] = fmaf(p, va.w, acc[3]);
      acc[4] = fmaf(p, vb.x, acc[4]);
      acc[5] = fmaf(p, vb.y, acc[5]);
      acc[6] = fmaf(p, vb.z, acc[6]);
      acc[7] = fmaf(p, vb.w, acc[7]);
    }
    __syncthreads();
  }

  float* pp = plds + (part * 32 + qlocal) * 9;
#pragma unroll
  for (int i = 0; i < 8; ++i) pp[i] = acc[i];
  pp[8] = ll;
  __syncthreads();

  if (tid < 32) {
    float o[8];
    float ls = 0.f;
#pragma unroll
    for (int i = 0; i < 8; ++i) o[i] = 0.f;
#pragma unroll
    for (int pr = 0; pr < 8; ++pr) {
      const float* q = plds + (pr * 32 + tid) * 9;
#pragma unroll
      for (int i = 0; i < 8; ++i) o[i] += q[i];
      ls += q[8];
    }
    const float inv = 1.0f / ls;
#pragma unroll
    for (int i = 0; i < 8; ++i) o[i] *= inv;
    const int mytok = batch * SS + chunk * 32 + tid;
    float at[8];
#pragma unroll
    for (int i = 0; i < 8; ++i) {
      float a = ws[O_BCOMB + i];
#pragma unroll
      for (int d = 0; d < 8; ++d) a = fmaf(o[d], ws[O_WCOMB + d * 8 + i], a);
      at[i] = a;
    }
    const float* xp = ws + O_X + mytok * 8;
    float z[8];
#pragma unroll
    for (int i = 0; i < 8; ++i) z[i] = xp[i] + at[i];
    float y[8];
    layernorm8(z, ws + O_G1, ws + O_BE1, y);
    float4* hp = reinterpret_cast<float4*>(hout + mytok * 8);
    hp[0] = make_float4(y[0], y[1], y[2], y[3]);
    hp[1] = make_float4(y[4], y[5], y[6], y[7]);
  }
}

__global__ __launch_bounds__(256) void ffn_ln2(const float* __restrict__ ws,
                                               void* __restrict__ out) {
  __shared__ float plds[4 * 64 * 8];
  const int tid = threadIdx.x;
  const int tok = blockIdx.x * 64 + (tid & 63);
  const int part = __builtin_amdgcn_readfirstlane(tid >> 6);

  const float* hp = ws + O_H + tok * 8;
  float4 h0 = *reinterpret_cast<const float4*>(hp);
  float4 h1 = *reinterpret_cast<const float4*>(hp + 4);
  float hv[8] = {h0.x, h0.y, h0.z, h0.w, h1.x, h1.y, h1.z, h1.w};

  float qin[8];
#pragma unroll
  for (int i = 0; i < 8; ++i) {
    float a = ws[O_BPREF + i];
#pragma unroll
    for (int d = 0; d < 8; ++d) a = fmaf(hv[d], ws[O_WPREF + d * 8 + i], a);
    qin[i] = a;
  }
  float qf[8];
  qproj(qin, ws + O_THF, qf);

  float acc[8];
#pragma unroll
  for (int i = 0; i < 8; ++i) acc[i] = 0.f;
  const float* w1t = ws + O_W1T + part * 1024 * 8;
  const float* b1f = ws + O_B1F + part * 1024;
  const float* w2f = ws + O_W2F + part * 1024 * 8;
#pragma unroll 4
  for (int j = 0; j < 1024; ++j) {
    float hj = b1f[j];
    const float* wa = w1t + j * 8;
#pragma unroll
    for (int d = 0; d < 8; ++d) hj = fmaf(qf[d], wa[d], hj);
    hj = fmaxf(hj, 0.f);
    const float* wb = w2f + j * 8;
#pragma unroll
    for (int d = 0; d < 8; ++d) acc[d] = fmaf(hj, wb[d], acc[d]);
  }

  float* pp = plds + part * 512 + (tid & 63) * 8;
#pragma unroll
  for (int d = 0; d < 8; ++d) pp[d] = acc[d];
  __syncthreads();

  if (tid < 64) {
    const int isf = (int)ws[O_FLAG];
    float f[8];
#pragma unroll
    for (int d = 0; d < 8; ++d)
      f[d] = ws[O_B2 + d] + plds[tid * 8 + d] + plds[512 + tid * 8 + d] +
             plds[1024 + tid * 8 + d] + plds[1536 + tid * 8 + d];
    float z[8];
#pragma unroll
    for (int d = 0; d < 8; ++d) z[d] = hv[d] + f[d];
    float y[8];
    layernorm8(z, ws + O_G2, ws + O_BE2, y);
    const int otok = blockIdx.x * 64 + tid;
    if (isf) {
      float4* op = reinterpret_cast<float4*>((float*)out + otok * 8);
      op[0] = make_float4(y[0], y[1], y[2], y[3]);
      op[1] = make_float4(y[4], y[5], y[6], y[7]);
    } else {
      uint4 o;
      o.x = (unsigned)f2bf(y[0]) | ((unsigned)f2bf(y[1]) << 16);
      o.y = (unsigned)f2bf(y[2]) | ((unsigned)f2bf(y[3]) << 16);
      o.z = (unsigned)f2bf(y[4]) | ((unsigned)f2bf(y[5]) << 16);
      o.w = (unsigned)f2bf(y[6]) | ((unsigned)f2bf(y[7]) << 16);
      *reinterpret_cast<uint4*>((unsigned short*)out + otok * 8) = o;
    }
  }
}

extern "C" void kernel_launch(void* const* d_in, const int* in_sizes, int n_in,
                              void* d_out, int out_size, void* d_ws, size_t ws_size,
                              hipStream_t stream) {
  float* ws = (float*)d_ws;
  const int mfma_ok = (ws_size >= WS_MFMA);

  prep_all<<<dim3(177), dim3(256), 0, stream>>>(
      d_in[0], d_in[1], d_in[2], d_in[3], d_in[4], d_in[5], d_in[6],
      d_in[7], d_in[8], d_in[9], d_in[10], d_in[11], d_in[12], d_in[13],
      d_in[14], d_in[15], d_in[16], d_in[17], d_in[18], ws, mfma_ok);

  if (mfma_ok) {
    attn_ffn_entry<<<dim3(256), dim3(1024), 0, stream>>>(d_in[0], ws, d_out);
  } else {
    attn_ln1<<<dim3(512), dim3(256), 0, stream>>>(ws, ws + O_H);
    ffn_ln2<<<dim3(256), dim3(256), 0, stream>>>(ws, d_out);
  }
}

// Round 15
// 30.080 us; speedup vs baseline: 1.1223x; 1.1047x over previous
//
#include <hip/hip_runtime.h>
#include <hip/hip_bf16.h>

#define BB 8
#define SS 2048
#define EE 8
#define FF 4096
#define NTOK (BB*SS)

using bf16x8 = __attribute__((ext_vector_type(8))) short;
using f32x4  = __attribute__((ext_vector_type(4))) float;

// ---- workspace layout (float offsets) ----
constexpr int O_FLAG  = 0;
constexpr int O_WPRE  = 8;      // 64
constexpr int O_BPRE  = 72;     // 8
constexpr int O_THQ   = 80;     // 8
constexpr int O_THK   = 88;     // 8
constexpr int O_THV   = 96;     // 8
constexpr int O_WCOMB = 104;    // 64
constexpr int O_BCOMB = 168;    // 8
constexpr int O_G1    = 176;    // 8
constexpr int O_BE1   = 184;    // 8
constexpr int O_G2    = 192;    // 8
constexpr int O_BE2   = 200;    // 8
constexpr int O_WPREF = 208;    // 64
constexpr int O_BPREF = 272;    // 8
constexpr int O_THF   = 280;    // 8
constexpr int O_B2    = 288;    // 8
constexpr int O_W1T   = 512;             // fallback
constexpr int O_B1F   = O_W1T + FF*8;
constexpr int O_W2F   = O_B1F + FF;
constexpr int O_X     = O_W2F + FF*8;    // fallback path only
constexpr int O_K     = O_X + NTOK*EE;   // fallback attn
constexpr int O_V     = O_K + NTOK*EE;   // fallback attn
constexpr int O_H     = O_V + NTOK*EE;   // fallback
constexpr int O_P     = O_H + NTOK*EE;   // unused (layout stability)
constexpr int O_QFB   = O_P + 8*NTOK*EE; // unused on fused path
constexpr int O_W1A   = O_QFB + NTOK*4;  // 65536 f
constexpr int O_W2B   = O_W1A + 65536;   // 32768 f
constexpr int O_QB    = O_W2B + 32768;   // NTOK*4
constexpr int O_KB    = O_QB + NTOK*4;   // NTOK*4
constexpr int O_VTB   = O_KB + NTOK*4;   // 65536 f
constexpr size_t WS_MFMA = (size_t)(O_VTB + 65536) * 4;

__device__ __forceinline__ float b2f(unsigned short u) {
  return __uint_as_float(((unsigned)u) << 16);
}

__device__ __forceinline__ unsigned short f2bf(float f) {
  unsigned u = __float_as_uint(f);
  unsigned r = (u + 0x7fffu + ((u >> 16) & 1u)) >> 16;
  return (unsigned short)r;
}

// pack two f32 -> bf16x2 (a at low half = element 0)
__device__ __forceinline__ unsigned pk2(float a, float b) {
  unsigned ua = __float_as_uint(a) + 0x8000u;
  unsigned ub = __float_as_uint(b) + 0x8000u;
  return __builtin_amdgcn_perm(ub, ua, 0x07060302u);
}

__device__ __forceinline__ float loadin(const void* p, int i, int isf) {
  if (isf) return reinterpret_cast<const float*>(p)[i];
  return b2f(reinterpret_cast<const unsigned short*>(p)[i]);
}

// vectorized 8-element input row load (token granularity)
__device__ __forceinline__ void loadx8(const void* x, int tok, int isf, float* xv) {
  if (isf) {
    float4 a = reinterpret_cast<const float4*>(x)[tok * 2];
    float4 b = reinterpret_cast<const float4*>(x)[tok * 2 + 1];
    xv[0] = a.x; xv[1] = a.y; xv[2] = a.z; xv[3] = a.w;
    xv[4] = b.x; xv[5] = b.y; xv[6] = b.z; xv[7] = b.w;
  } else {
    uint4 u = reinterpret_cast<const uint4*>(x)[tok];
    xv[0] = __uint_as_float(u.x << 16); xv[1] = __uint_as_float(u.x & 0xffff0000u);
    xv[2] = __uint_as_float(u.y << 16); xv[3] = __uint_as_float(u.y & 0xffff0000u);
    xv[4] = __uint_as_float(u.z << 16); xv[5] = __uint_as_float(u.z & 0xffff0000u);
    xv[6] = __uint_as_float(u.w << 16); xv[7] = __uint_as_float(u.w & 0xffff0000u);
  }
}

// Wave-cooperative dtype sniff (see earlier rounds); P(misdetect)~2e-17.
__device__ __forceinline__ int detect_f32_wave(const void* x) {
  unsigned u = reinterpret_cast<const unsigned*>(x)[threadIdx.x & 63];
  float v = b2f((unsigned short)u);
  int bad = !(fabsf(v) <= 1e4f);
  return __ballot(bad) != 0ull;
}

// <Z_k>: c = cos(z+theta); out_k = prod_{i<=k} c_i (k>=1); out_0 = prod_{i=1..7} c_i
__device__ __forceinline__ void qproj(const float* qin, const float* th, float* out) {
  float c[8];
#pragma unroll
  for (int i = 0; i < 8; ++i) c[i] = __cosf(qin[i] + th[i]);
  float p = c[1];
#pragma unroll
  for (int i = 2; i < 8; ++i) p *= c[i];
  out[0] = p;
  float r = c[0];
#pragma unroll
  for (int i = 1; i < 8; ++i) { r *= c[i]; out[i] = r; }
}

__device__ __forceinline__ void layernorm8(const float* z, const float* g, const float* b, float* y) {
  float m = 0.f;
#pragma unroll
  for (int i = 0; i < 8; ++i) m += z[i];
  m *= 0.125f;
  float v = 0.f;
#pragma unroll
  for (int i = 0; i < 8; ++i) { float d = z[i] - m; v += d * d; }
  v *= 0.125f;
  float rs = rsqrtf(v + 1e-5f);
#pragma unroll
  for (int i = 0; i < 8; ++i) y[i] = (z[i] - m) * rs * g[i] + b[i];
}

// ==== prep helpers (proven) ====

__device__ __forceinline__ void prep_token_mfma(
    int tok, const void* x, const void* w_pre, const void* b_pre,
    const void* th_q, const void* th_k, const void* th_v,
    float* __restrict__ ws, int isf) {
  float xv[8];
  loadx8(x, tok, isf, xv);
  float qin[8];
#pragma unroll
  for (int i = 0; i < 8; ++i) {
    float a = loadin(b_pre, i, isf);
#pragma unroll
    for (int d = 0; d < 8; ++d) a = fmaf(xv[d], loadin(w_pre, d * 8 + i, isf), a);
    qin[i] = a;
  }
  float thq[8], thk[8], thv[8];
#pragma unroll
  for (int i = 0; i < 8; ++i) {
    thq[i] = loadin(th_q, i, isf);
    thk[i] = loadin(th_k, i, isf);
    thv[i] = loadin(th_v, i, isf);
  }
  float qv[8], kv[8], vv[8];
  qproj(qin, thq, qv);
  qproj(qin, thk, kv);
  qproj(qin, thv, vv);
  const float sc = 0.510120927f;  // log2(e)/sqrt(8)
  uint4 uq, uk;
  uq.x = (unsigned)f2bf(qv[0] * sc) | ((unsigned)f2bf(qv[1] * sc) << 16);
  uq.y = (unsigned)f2bf(qv[2] * sc) | ((unsigned)f2bf(qv[3] * sc) << 16);
  uq.z = (unsigned)f2bf(qv[4] * sc) | ((unsigned)f2bf(qv[5] * sc) << 16);
  uq.w = (unsigned)f2bf(qv[6] * sc) | ((unsigned)f2bf(qv[7] * sc) << 16);
  uk.x = (unsigned)f2bf(kv[0]) | ((unsigned)f2bf(kv[1]) << 16);
  uk.y = (unsigned)f2bf(kv[2]) | ((unsigned)f2bf(kv[3]) << 16);
  uk.z = (unsigned)f2bf(kv[4]) | ((unsigned)f2bf(kv[5]) << 16);
  uk.w = (unsigned)f2bf(kv[6]) | ((unsigned)f2bf(kv[7]) << 16);
  reinterpret_cast<uint4*>(ws + O_QB)[tok] = uq;
  reinterpret_cast<uint4*>(ws + O_KB)[tok] = uk;
  unsigned short* vtb = reinterpret_cast<unsigned short*>(ws + O_VTB);
#pragma unroll
  for (int i = 0; i < 8; ++i) vtb[i * NTOK + tok] = f2bf(vv[i]);
}

__device__ __forceinline__ void prep_w1a(int idx, const void* w1, const void* b1,
                                         float* __restrict__ ws, int isf) {
  const int T = idx >> 6, l = idx & 63, c = l & 15, g = l >> 4;
  const int j = T * 16 + c;
  float f[8];
#pragma unroll
  for (int e = 0; e < 8; ++e) f[e] = 0.f;
  if (g == 0) {
#pragma unroll
    for (int e = 0; e < 8; ++e) f[e] = loadin(w1, e * FF + j, isf);
  } else if (g == 1) {
    f[0] = loadin(b1, j, isf);
  }
  uint4 u;
  u.x = (unsigned)f2bf(f[0]) | ((unsigned)f2bf(f[1]) << 16);
  u.y = (unsigned)f2bf(f[2]) | ((unsigned)f2bf(f[3]) << 16);
  u.z = (unsigned)f2bf(f[4]) | ((unsigned)f2bf(f[5]) << 16);
  u.w = (unsigned)f2bf(f[6]) | ((unsigned)f2bf(f[7]) << 16);
  reinterpret_cast<uint4*>(ws + O_W1A)[idx] = u;
}

__device__ __forceinline__ void prep_w2b(int idx2, const void* w2,
                                         float* __restrict__ ws, int isf) {
  const int W = idx2 >> 6, l = idx2 & 63, i = l & 15, g = l >> 4;
  float f[8];
#pragma unroll
  for (int e = 0; e < 8; ++e) f[e] = 0.f;
  if (i < 8) {
#pragma unroll
    for (int e = 0; e < 8; ++e) {
      const int j = W * 32 + 16 * (e >> 2) + 4 * g + (e & 3);  // pi-permutation
      f[e] = loadin(w2, j * 8 + i, isf);
    }
  }
  uint4 u;
  u.x = (unsigned)f2bf(f[0]) | ((unsigned)f2bf(f[1]) << 16);
  u.y = (unsigned)f2bf(f[2]) | ((unsigned)f2bf(f[3]) << 16);
  u.z = (unsigned)f2bf(f[4]) | ((unsigned)f2bf(f[5]) << 16);
  u.w = (unsigned)f2bf(f[6]) | ((unsigned)f2bf(f[7]) << 16);
  reinterpret_cast<uint4*>(ws + O_W2B)[idx2] = u;
}

// ---- kernel A (fused prep): grid 177 x 256 (proven) ----
__global__ __launch_bounds__(256) void prep_all(
    const void* x, const void* w_pre, const void* b_pre, const void* th_q,
    const void* th_k, const void* th_v, const void* w_comb, const void* b_comb,
    const void* g1, const void* be1, const void* g2, const void* be2,
    const void* w_pre_f, const void* b_pre_f, const void* th_f,
    const void* w1, const void* b1, const void* w2, const void* b2,
    float* __restrict__ ws, int mfma_ok) {
  const int bid = blockIdx.x, tid = threadIdx.x;
  const int isf = detect_f32_wave(x);
  if (bid < 64) {
    const int tok = bid * 256 + tid;
    if (mfma_ok) {
      prep_token_mfma(tok, x, w_pre, b_pre, th_q, th_k, th_v, ws, isf);
    } else {
      float xv[8];
      loadx8(x, tok, isf, xv);
      float qin[8];
#pragma unroll
      for (int i = 0; i < 8; ++i) {
        float a = loadin(b_pre, i, isf);
#pragma unroll
        for (int d = 0; d < 8; ++d) a = fmaf(xv[d], loadin(w_pre, d * 8 + i, isf), a);
        qin[i] = a;
      }
      float thq[8], thk[8], thv[8];
#pragma unroll
      for (int i = 0; i < 8; ++i) {
        thq[i] = loadin(th_q, i, isf);
        thk[i] = loadin(th_k, i, isf);
        thv[i] = loadin(th_v, i, isf);
      }
      float qv[8], kv[8], vv[8];
      qproj(qin, thq, qv);
      qproj(qin, thk, kv);
      qproj(qin, thv, vv);
      float4* xp = reinterpret_cast<float4*>(ws + O_X + tok * 8);
      xp[0] = make_float4(xv[0], xv[1], xv[2], xv[3]);
      xp[1] = make_float4(xv[4], xv[5], xv[6], xv[7]);
      float4* kp = reinterpret_cast<float4*>(ws + O_K + tok * 8);
      float4* vp = reinterpret_cast<float4*>(ws + O_V + tok * 8);
      kp[0] = make_float4(kv[0], kv[1], kv[2], kv[3]);
      kp[1] = make_float4(kv[4], kv[5], kv[6], kv[7]);
      vp[0] = make_float4(vv[0], vv[1], vv[2], vv[3]);
      vp[1] = make_float4(vv[4], vv[5], vv[6], vv[7]);
    }
  } else if (bid < 128) {
    if (!mfma_ok) return;
    prep_w1a((bid - 64) * 256 + tid, w1, b1, ws, isf);
  } else if (bid < 160) {
    if (!mfma_ok) return;
    prep_w2b((bid - 128) * 256 + tid, w2, ws, isf);
  } else if (bid == 160) {
    if (tid < 64) {
      ws[O_WPRE + tid]  = loadin(w_pre, tid, isf);
      ws[O_WCOMB + tid] = loadin(w_comb, tid, isf);
      ws[O_WPREF + tid] = loadin(w_pre_f, tid, isf);
    }
    if (tid < 8) {
      ws[O_BPRE + tid]  = loadin(b_pre, tid, isf);
      ws[O_THQ + tid]   = loadin(th_q, tid, isf);
      ws[O_THK + tid]   = loadin(th_k, tid, isf);
      ws[O_THV + tid]   = loadin(th_v, tid, isf);
      ws[O_BCOMB + tid] = loadin(b_comb, tid, isf);
      ws[O_G1 + tid]    = loadin(g1, tid, isf);
      ws[O_BE1 + tid]   = loadin(be1, tid, isf);
      ws[O_G2 + tid]    = loadin(g2, tid, isf);
      ws[O_BE2 + tid]   = loadin(be2, tid, isf);
      ws[O_BPREF + tid] = loadin(b_pre_f, tid, isf);
      ws[O_THF + tid]   = loadin(th_f, tid, isf);
      ws[O_B2 + tid]    = loadin(b2, tid, isf);
    }
    if (tid == 0) ws[O_FLAG] = (float)isf;
  } else {
    if (mfma_ok) return;
    const int j = (bid - 161) * 256 + tid;
    ws[O_B1F + j] = loadin(b1, j, isf);
#pragma unroll
    for (int i = 0; i < 8; ++i) {
      ws[O_W1T + j * 8 + i] = loadin(w1, i * FF + j, isf);
      ws[O_W2F + j * 8 + i] = loadin(w2, j * 8 + i, isf);
    }
  }
}

// ==== fused attn+ffn body, 32 tokens/block (R11-proven, best-measured) ====
// grid 512 x 512 (8 waves, 2 blocks/CU -> cross-block phase overlap).
__device__ __forceinline__ void attn_ffn_body(const void* __restrict__ x,
                                              const float* __restrict__ ws,
                                              void* __restrict__ out, int isf) {
  __shared__ float Olds[8][32][8];     // 8 KB
  __shared__ float Llds[8][32];        // 1 KB
  __shared__ float Hlds[32][8];        // 1 KB
  __shared__ unsigned Qflds[32 * 4];   // 0.5 KB
  const int tid = threadIdx.x;
  const int wv = tid >> 6, l = tid & 63;
  const int c = l & 15, g = l >> 4;
  const int tokbase = blockIdx.x * 32;
  const int batch = blockIdx.x >> 6;   // 64 blocks per batch

  const bf16x8 zerov = (bf16x8)(short)0;
  const f32x4 zero = {0.f, 0.f, 0.f, 0.f};

  // ---- phase 1: attention (wave wv covers keys [batch*SS + wv*256, +256)) ----
  bf16x8 qb0 = zerov, qb1 = zerov;
  if (g == 0) {
    const bf16x8* qp = reinterpret_cast<const bf16x8*>(ws + O_QB) + tokbase + c;
    qb0 = qp[0]; qb1 = qp[16];
  }
  const bf16x8* Kb = reinterpret_cast<const bf16x8*>(ws + O_KB);
  const unsigned short* vtb = reinterpret_cast<const unsigned short*>(ws + O_VTB);

  f32x4 oacc0 = zero, oacc1 = zero;
  float ls0 = 0.f, ls1 = 0.f;
  const int kbase = batch * SS + wv * 256;

  for (int w = 0; w < 8; ++w) {
    const int kt = kbase + w * 32;
    bf16x8 kf0 = zerov, kf1 = zerov;
    if (g == 0) {
      kf0 = Kb[kt + c];
      kf1 = Kb[kt + 16 + c];
    }
    union { uint2 u[2]; bf16x8 v; } VF;
    VF.u[0] = make_uint2(0u, 0u);
    VF.u[1] = make_uint2(0u, 0u);
    if (c < 8) {
      VF.u[0] = *reinterpret_cast<const uint2*>(vtb + c * NTOK + kt + 4 * g);
      VF.u[1] = *reinterpret_cast<const uint2*>(vtb + c * NTOK + kt + 16 + 4 * g);
    }
#define ATT_QT(QB, OACC, LS)                                                     \
    {                                                                            \
      f32x4 s0 = __builtin_amdgcn_mfma_f32_16x16x32_bf16(kf0, QB, zero, 0,0,0);  \
      f32x4 s1 = __builtin_amdgcn_mfma_f32_16x16x32_bf16(kf1, QB, zero, 0,0,0);  \
      float p0[4], p1[4];                                                        \
      _Pragma("unroll")                                                          \
      for (int r = 0; r < 4; ++r) {                                              \
        p0[r] = __builtin_amdgcn_exp2f(s0[r]);                                   \
        p1[r] = __builtin_amdgcn_exp2f(s1[r]);                                   \
        LS += p0[r] + p1[r];                                                     \
      }                                                                          \
      union { unsigned u[4]; bf16x8 v; } PA;                                     \
      PA.u[0] = pk2(p0[0], p0[1]);                                               \
      PA.u[1] = pk2(p0[2], p0[3]);                                               \
      PA.u[2] = pk2(p1[0], p1[1]);                                               \
      PA.u[3] = pk2(p1[2], p1[3]);                                               \
      OACC = __builtin_amdgcn_mfma_f32_16x16x32_bf16(PA.v, VF.v, OACC, 0, 0, 0); \
    }
    ATT_QT(qb0, oacc0, ls0)
    ATT_QT(qb1, oacc1, ls1)
#undef ATT_QT
  }

  ls0 += __shfl_xor(ls0, 16); ls0 += __shfl_xor(ls0, 32);
  ls1 += __shfl_xor(ls1, 16); ls1 += __shfl_xor(ls1, 32);
  if (l < 16) {
    Llds[wv][l]      = ls0;
    Llds[wv][16 + l] = ls1;
  }
  if (c < 8) {
#pragma unroll
    for (int r = 0; r < 4; ++r) {
      Olds[wv][ 0 + 4 * g + r][c] = oacc0[r];
      Olds[wv][16 + 4 * g + r][c] = oacc1[r];
    }
  }
  __syncthreads();

  // ---- epilogue 1: combine, w_comb, residual, LN1, QF -> LDS ----
  if (tid < 32) {
    const int mytok = tokbase + tid;
    float lv = 0.f;
    float o[8];
#pragma unroll
    for (int i = 0; i < 8; ++i) o[i] = 0.f;
#pragma unroll
    for (int w = 0; w < 8; ++w) {
      lv += Llds[w][tid];
#pragma unroll
      for (int i = 0; i < 8; ++i) o[i] += Olds[w][tid][i];
    }
    const float inv = 1.0f / lv;
#pragma unroll
    for (int i = 0; i < 8; ++i) o[i] *= inv;
    float at[8];
#pragma unroll
    for (int i = 0; i < 8; ++i) {
      float a = ws[O_BCOMB + i];
#pragma unroll
      for (int d = 0; d < 8; ++d) a = fmaf(o[d], ws[O_WCOMB + d * 8 + i], a);
      at[i] = a;
    }
    float xv[8];
    loadx8(x, mytok, isf, xv);
    float z[8];
#pragma unroll
    for (int i = 0; i < 8; ++i) z[i] = xv[i] + at[i];
    float y[8];
    layernorm8(z, ws + O_G1, ws + O_BE1, y);
#pragma unroll
    for (int i = 0; i < 8; ++i) Hlds[tid][i] = y[i];
    float qin2[8];
#pragma unroll
    for (int i = 0; i < 8; ++i) {
      float a = ws[O_BPREF + i];
#pragma unroll
      for (int d = 0; d < 8; ++d) a = fmaf(y[d], ws[O_WPREF + d * 8 + i], a);
      qin2[i] = a;
    }
    float qfv[8];
    qproj(qin2, ws + O_THF, qfv);
    Qflds[tid * 4 + 0] = (unsigned)f2bf(qfv[0]) | ((unsigned)f2bf(qfv[1]) << 16);
    Qflds[tid * 4 + 1] = (unsigned)f2bf(qfv[2]) | ((unsigned)f2bf(qfv[3]) << 16);
    Qflds[tid * 4 + 2] = (unsigned)f2bf(qfv[4]) | ((unsigned)f2bf(qfv[5]) << 16);
    Qflds[tid * 4 + 3] = (unsigned)f2bf(qfv[6]) | ((unsigned)f2bf(qfv[7]) << 16);
  }
  __syncthreads();

  // ---- phase 2: FFN (wave wv owns j-range [wv*512, +512), 2 token-frags) ----
  bf16x8 qfb0 = (bf16x8)(short)0, qfb1 = qfb0;
  if (g == 0) {
    const bf16x8* qp = reinterpret_cast<const bf16x8*>(Qflds) + c;
    qfb0 = qp[0]; qfb1 = qp[16];
  } else if (g == 1) {
    qfb0[0] = (short)0x3F80; qfb1[0] = (short)0x3F80;
  }

  const bf16x8* w1a = reinterpret_cast<const bf16x8*>(ws + O_W1A) + l;
  const bf16x8* w2b = reinterpret_cast<const bf16x8*>(ws + O_W2B) + l;
  f32x4 acc0 = zero, acc1 = zero;

  bf16x8 W10 = w1a[(wv * 32 + 0) * 64], W11 = w1a[(wv * 32 + 1) * 64];
  bf16x8 W12 = w1a[(wv * 32 + 2) * 64], W13 = w1a[(wv * 32 + 3) * 64];
  bf16x8 W20 = w2b[(wv * 16 + 0) * 64], W21 = w2b[(wv * 16 + 1) * 64];

  for (int jt = 0; jt < 8; ++jt) {
    bf16x8 nW10, nW11, nW12, nW13, nW20, nW21;
    if (jt < 7) {
      const int Tb = wv * 32 + (jt + 1) * 4;
      const int Wb = wv * 16 + (jt + 1) * 2;
      nW10 = w1a[(Tb + 0) * 64]; nW11 = w1a[(Tb + 1) * 64];
      nW12 = w1a[(Tb + 2) * 64]; nW13 = w1a[(Tb + 3) * 64];
      nW20 = w2b[(Wb + 0) * 64]; nW21 = w2b[(Wb + 1) * 64];
    }
#define FFN_TOK(QF, ACC)                                                        \
    {                                                                           \
      f32x4 p0 = __builtin_amdgcn_mfma_f32_16x16x32_bf16(W10, QF, zero, 0,0,0); \
      f32x4 p1 = __builtin_amdgcn_mfma_f32_16x16x32_bf16(W11, QF, zero, 0,0,0); \
      f32x4 p2 = __builtin_amdgcn_mfma_f32_16x16x32_bf16(W12, QF, zero, 0,0,0); \
      f32x4 p3 = __builtin_amdgcn_mfma_f32_16x16x32_bf16(W13, QF, zero, 0,0,0); \
      union { unsigned u[4]; bf16x8 v; } A0, A1;                                \
      A0.u[0] = pk2(fmaxf(p0[0], 0.f), fmaxf(p0[1], 0.f));                      \
      A0.u[1] = pk2(fmaxf(p0[2], 0.f), fmaxf(p0[3], 0.f));                      \
      A0.u[2] = pk2(fmaxf(p1[0], 0.f), fmaxf(p1[1], 0.f));                      \
      A0.u[3] = pk2(fmaxf(p1[2], 0.f), fmaxf(p1[3], 0.f));                      \
      A1.u[0] = pk2(fmaxf(p2[0], 0.f), fmaxf(p2[1], 0.f));                      \
      A1.u[1] = pk2(fmaxf(p2[2], 0.f), fmaxf(p2[3], 0.f));                      \
      A1.u[2] = pk2(fmaxf(p3[0], 0.f), fmaxf(p3[1], 0.f));                      \
      A1.u[3] = pk2(fmaxf(p3[2], 0.f), fmaxf(p3[3], 0.f));                      \
      ACC = __builtin_amdgcn_mfma_f32_16x16x32_bf16(A0.v, W20, ACC, 0, 0, 0);   \
      ACC = __builtin_amdgcn_mfma_f32_16x16x32_bf16(A1.v, W21, ACC, 0, 0, 0);   \
    }
    FFN_TOK(qfb0, acc0)
    FFN_TOK(qfb1, acc1)
#undef FFN_TOK
    if (jt < 7) {
      W10 = nW10; W11 = nW11; W12 = nW12; W13 = nW13;
      W20 = nW20; W21 = nW21;
    }
  }

  if (c < 8) {
#pragma unroll
    for (int r = 0; r < 4; ++r) {
      Olds[wv][ 0 + 4 * g + r][c] = acc0[r];
      Olds[wv][16 + 4 * g + r][c] = acc1[r];
    }
  }
  __syncthreads();

  // ---- epilogue 2: reduce, b2, residual, LN2 -> out ----
  if (tid < 32) {
    const int tok = tokbase + tid;
    float f[8];
#pragma unroll
    for (int d = 0; d < 8; ++d) {
      float s = ws[O_B2 + d];
#pragma unroll
      for (int w = 0; w < 8; ++w) s += Olds[w][tid][d];
      f[d] = s;
    }
    float z[8];
#pragma unroll
    for (int d = 0; d < 8; ++d) z[d] = Hlds[tid][d] + f[d];
    float y[8];
    layernorm8(z, ws + O_G2, ws + O_BE2, y);
    if (isf) {
      float4* op = reinterpret_cast<float4*>((float*)out + tok * 8);
      op[0] = make_float4(y[0], y[1], y[2], y[3]);
      op[1] = make_float4(y[4], y[5], y[6], y[7]);
    } else {
      uint4 o;
      o.x = (unsigned)f2bf(y[0]) | ((unsigned)f2bf(y[1]) << 16);
      o.y = (unsigned)f2bf(y[2]) | ((unsigned)f2bf(y[3]) << 16);
      o.z = (unsigned)f2bf(y[4]) | ((unsigned)f2bf(y[5]) << 16);
      o.w = (unsigned)f2bf(y[6]) | ((unsigned)f2bf(y[7]) << 16);
      *reinterpret_cast<uint4*>((unsigned short*)out + tok * 8) = o;
    }
  }
}

__global__ __launch_bounds__(512) void attn_ffn_entry(const void* __restrict__ x,
                                                      const float* __restrict__ ws,
                                                      void* __restrict__ out) {
  const int isf = detect_f32_wave(x);
  attn_ffn_body(x, ws, out, isf);
}

// ---- scalar fallbacks (proven round-2 path, ws-too-small case) ----
__global__ __launch_bounds__(256) void attn_ln1(const float* __restrict__ ws,
                                                float* __restrict__ hout) {
  __shared__ float Kt[512 * 8];
  __shared__ float Vt[512 * 8];
  __shared__ float plds[8 * 32 * 9];
  const int tid = threadIdx.x;
  const int batch = blockIdx.x >> 6;
  const int chunk = blockIdx.x & 63;
  const int qlocal = tid & 31;
  const int part = tid >> 5;
  const int tok = batch * SS + chunk * 32 + qlocal;

  float qs[8];
  {
    const float* xp = ws + O_X + tok * 8;
    float qin[8];
#pragma unroll
    for (int i = 0; i < 8; ++i) {
      float a = ws[O_BPRE + i];
#pragma unroll
      for (int d = 0; d < 8; ++d) a = fmaf(xp[d], ws[O_WPRE + d * 8 + i], a);
      qin[i] = a;
    }
    float qv[8];
    qproj(qin, ws + O_THQ, qv);
#pragma unroll
    for (int i = 0; i < 8; ++i) qs[i] = qv[i] * 0.510120927f;
  }

  float ll = 0.f;
  float acc[8];
#pragma unroll
  for (int i = 0; i < 8; ++i) acc[i] = 0.f;

  for (int t = 0; t < 4; ++t) {
    const float4* Kg = reinterpret_cast<const float4*>(ws + O_K + (batch * SS + t * 512) * 8);
    const float4* Vg = reinterpret_cast<const float4*>(ws + O_V + (batch * SS + t * 512) * 8);
    float4* Kt4 = reinterpret_cast<float4*>(Kt);
    float4* Vt4 = reinterpret_cast<float4*>(Vt);
#pragma unroll
    for (int i = 0; i < 4; ++i) {
      Kt4[i * 256 + tid] = Kg[i * 256 + tid];
      Vt4[i * 256 + tid] = Vg[i * 256 + tid];
    }
    __syncthreads();
    const float* Kp = Kt + part * 64 * 8;
    const float* Vp = Vt + part * 64 * 8;
#pragma unroll 2
    for (int k = 0; k < 64; ++k) {
      float4 ka = *reinterpret_cast<const float4*>(Kp + k * 8);
      float4 kb = *reinterpret_cast<const float4*>(Kp + k * 8 + 4);
      float s = ((qs[0] * ka.x + qs[1] * ka.y) + (qs[2] * ka.z + qs[3] * ka.w)) +
                ((qs[4] * kb.x + qs[5] * kb.y) + (qs[6] * kb.z + qs[7] * kb.w));
      float p = __builtin_amdgcn_exp2f(s);
      ll += p;
      float4 va = *reinterpret_cast<const float4*>(Vp + k * 8);
      float4 vb = *reinterpret_cast<const float4*>(Vp + k * 8 + 4);
      acc[0] = fmaf(p, va.x, acc[0]);
      acc[1] = fmaf(p, va.y, acc[1]);
      acc[2] = fmaf(p, va.z, acc[2]);
      acc[3] = fmaf(p, va.w, acc[3]);
      acc[4] = fmaf(p, vb.x, acc[4]);
      acc[5] = fmaf(p, vb.y, acc[5]);
      acc[6] = fmaf(p, vb.z, acc[6]);
      acc[7] = fmaf(p, vb.w, acc[7]);
    }
    __syncthreads();
  }

  float* pp = plds + (part * 32 + qlocal) * 9;
#pragma unroll
  for (int i = 0; i < 8; ++i) pp[i] = acc[i];
  pp[8] = ll;
  __syncthreads();

  if (tid < 32) {
    float o[8];
    float ls = 0.f;
#pragma unroll
    for (int i = 0; i < 8; ++i) o[i] = 0.f;
#pragma unroll
    for (int pr = 0; pr < 8; ++pr) {
      const float* q = plds + (pr * 32 + tid) * 9;
#pragma unroll
      for (int i = 0; i < 8; ++i) o[i] += q[i];
      ls += q[8];
    }
    const float inv = 1.0f / ls;
#pragma unroll
    for (int i = 0; i < 8; ++i) o[i] *= inv;
    const int mytok = batch * SS + chunk * 32 + tid;
    float at[8];
#pragma unroll
    for (int i = 0; i < 8; ++i) {
      float a = ws[O_BCOMB + i];
#pragma unroll
      for (int d = 0; d < 8; ++d) a = fmaf(o[d], ws[O_WCOMB + d * 8 + i], a);
      at[i] = a;
    }
    const float* xp = ws + O_X + mytok * 8;
    float z[8];
#pragma unroll
    for (int i = 0; i < 8; ++i) z[i] = xp[i] + at[i];
    float y[8];
    layernorm8(z, ws + O_G1, ws + O_BE1, y);
    float4* hp = reinterpret_cast<float4*>(hout + mytok * 8);
    hp[0] = make_float4(y[0], y[1], y[2], y[3]);
    hp[1] = make_float4(y[4], y[5], y[6], y[7]);
  }
}

__global__ __launch_bounds__(256) void ffn_ln2(const float* __restrict__ ws,
                                               void* __restrict__ out) {
  __shared__ float plds[4 * 64 * 8];
  const int tid = threadIdx.x;
  const int tok = blockIdx.x * 64 + (tid & 63);
  const int part = __builtin_amdgcn_readfirstlane(tid >> 6);

  const float* hp = ws + O_H + tok * 8;
  float4 h0 = *reinterpret_cast<const float4*>(hp);
  float4 h1 = *reinterpret_cast<const float4*>(hp + 4);
  float hv[8] = {h0.x, h0.y, h0.z, h0.w, h1.x, h1.y, h1.z, h1.w};

  float qin[8];
#pragma unroll
  for (int i = 0; i < 8; ++i) {
    float a = ws[O_BPREF + i];
#pragma unroll
    for (int d = 0; d < 8; ++d) a = fmaf(hv[d], ws[O_WPREF + d * 8 + i], a);
    qin[i] = a;
  }
  float qf[8];
  qproj(qin, ws + O_THF, qf);

  float acc[8];
#pragma unroll
  for (int i = 0; i < 8; ++i) acc[i] = 0.f;
  const float* w1t = ws + O_W1T + part * 1024 * 8;
  const float* b1f = ws + O_B1F + part * 1024;
  const float* w2f = ws + O_W2F + part * 1024 * 8;
#pragma unroll 4
  for (int j = 0; j < 1024; ++j) {
    float hj = b1f[j];
    const float* wa = w1t + j * 8;
#pragma unroll
    for (int d = 0; d < 8; ++d) hj = fmaf(qf[d], wa[d], hj);
    hj = fmaxf(hj, 0.f);
    const float* wb = w2f + j * 8;
#pragma unroll
    for (int d = 0; d < 8; ++d) acc[d] = fmaf(hj, wb[d], acc[d]);
  }

  float* pp = plds + part * 512 + (tid & 63) * 8;
#pragma unroll
  for (int d = 0; d < 8; ++d) pp[d] = acc[d];
  __syncthreads();

  if (tid < 64) {
    const int isf = (int)ws[O_FLAG];
    float f[8];
#pragma unroll
    for (int d = 0; d < 8; ++d)
      f[d] = ws[O_B2 + d] + plds[tid * 8 + d] + plds[512 + tid * 8 + d] +
             plds[1024 + tid * 8 + d] + plds[1536 + tid * 8 + d];
    float z[8];
#pragma unroll
    for (int d = 0; d < 8; ++d) z[d] = hv[d] + f[d];
    float y[8];
    layernorm8(z, ws + O_G2, ws + O_BE2, y);
    const int otok = blockIdx.x * 64 + tid;
    if (isf) {
      float4* op = reinterpret_cast<float4*>((float*)out + otok * 8);
      op[0] = make_float4(y[0], y[1], y[2], y[3]);
      op[1] = make_float4(y[4], y[5], y[6], y[7]);
    } else {
      uint4 o;
      o.x = (unsigned)f2bf(y[0]) | ((unsigned)f2bf(y[1]) << 16);
      o.y = (unsigned)f2bf(y[2]) | ((unsigned)f2bf(y[3]) << 16);
      o.z = (unsigned)f2bf(y[4]) | ((unsigned)f2bf(y[5]) << 16);
      o.w = (unsigned)f2bf(y[6]) | ((unsigned)f2bf(y[7]) << 16);
      *reinterpret_cast<uint4*>((unsigned short*)out + otok * 8) = o;
    }
  }
}

extern "C" void kernel_launch(void* const* d_in, const int* in_sizes, int n_in,
                              void* d_out, int out_size, void* d_ws, size_t ws_size,
                              hipStream_t stream) {
  float* ws = (float*)d_ws;
  const int mfma_ok = (ws_size >= WS_MFMA);

  prep_all<<<dim3(177), dim3(256), 0, stream>>>(
      d_in[0], d_in[1], d_in[2], d_in[3], d_in[4], d_in[5], d_in[6],
      d_in[7], d_in[8], d_in[9], d_in[10], d_in[11], d_in[12], d_in[13],
      d_in[14], d_in[15], d_in[16], d_in[17], d_in[18], ws, mfma_ok);

  if (mfma_ok) {
    attn_ffn_entry<<<dim3(512), dim3(512), 0, stream>>>(d_in[0], ws, d_out);
  } else {
    attn_ln1<<<dim3(512), dim3(256), 0, stream>>>(ws, ws + O_H);
    ffn_ln2<<<dim3(256), dim3(256), 0, stream>>>(ws, d_out);
  }
}